// Round 8
// baseline (218.434 us; speedup 1.0000x reference)
//
#include <hip/hip_runtime.h>
#include <math.h>

#define T_LEN 3072
#define HID_DIM 2048
#define NH 16
#define NKV 8
#define HD 128
#define QKV_COLS ((NH + 2 * NKV) * HD)   // 4096
#define V_OFF (NH * HD + NKV * HD)       // 3072
#define RMS_EPS 1e-6f
#define NORM_EPS 1e-6f
#define THETA 10000.0f
#define SCALE 0.08838834764831845f       // 128^-0.5

#define BAND 256   // exp(-0.65*256)=e^-167 -> exactly 0 in f32; validated round 1
#define AQT 64     // q rows per attn block

typedef __attribute__((ext_vector_type(8))) _Float16 f16x8;
typedef __attribute__((ext_vector_type(4))) float f32x4;
typedef __attribute__((ext_vector_type(16))) float f32x16;

__device__ __forceinline__ void gload_lds16(const void* g, void* l) {
    __builtin_amdgcn_global_load_lds((const __attribute__((address_space(1))) void*)g,
                                     (__attribute__((address_space(3))) void*)l, 16, 0, 0);
}

// ---------------------------------------------------------------------------
// Balanced-grid f16 MFMA GEMM: C[M][N] = A[M][K] @ B[N][K]^T, f32 accumulate.
// Tile 192x128, 4 waves (2x2, per-wave 96x64), MFMA 32x32x16 (MI=3, NI=2).
// BK=32 K-steps, quad-buffered LDS (4 x 20KB = 80KB -> 2 blocks/CU),
// stage t+3 while computing t, counted vmcnt(10) (never 0 in steady state),
// one barrier per K-step. 64B LDS rows, chunk swizzle c^((row>>1)&3)
// (validated rounds 5-7, 0 bank conflicts).
// Grids: qkv 16x32=512 (=2/CU exactly), oproj 16x16=256 (=1/CU) -> balanced.
// SPLIT_V: blocks with bcol >= V_OFF write transposed into vt.
// ---------------------------------------------------------------------------
template <int M, int N, int K, typename OutT, bool SPLIT_V>
__global__ __launch_bounds__(256, 2) void gemm_192(const _Float16* __restrict__ A,
                                                   const _Float16* __restrict__ B,
                                                   OutT* __restrict__ C,
                                                   _Float16* __restrict__ vt) {
    constexpr int BM = 192, BN = 128;
    constexpr int NT = K / 32;
    constexpr int NX = N / BN;
    constexpr int ABUF = BM * 64;         // 12KB (192 rows x 32 f16)
    constexpr int BBUF = BN * 64;         // 8KB
    constexpr int BUFSZ = ABUF + BBUF;    // 20KB
    __shared__ char lds[4 * BUFSZ];       // 80KB

    const int tid = threadIdx.x, lane = tid & 63, wid = tid >> 6;
    const int wm = wid >> 1, wn = wid & 1;
    const int q8 = gridDim.x >> 3;
    const int sw = (blockIdx.x & 7) * q8 + (blockIdx.x >> 3);
    const int brow = (sw / NX) * BM, bcol = (sw % NX) * BN;

    auto stage = [&](int t) {
        const int k0 = t * 32;
        char* bufb = lds + (size_t)(t & 3) * BUFSZ;
#pragma unroll
        for (int j = 0; j < 3; ++j) {     // A: 3 issues x 64 rows
            const int row = j * 64 + (tid >> 2);
            const int c = (tid & 3) ^ ((row >> 1) & 3);
            gload_lds16(A + (size_t)(brow + row) * K + k0 + c * 8,
                        bufb + j * 4096 + tid * 16);
        }
#pragma unroll
        for (int j = 0; j < 2; ++j) {     // B: 2 issues x 64 rows
            const int row = j * 64 + (tid >> 2);
            const int c = (tid & 3) ^ ((row >> 1) & 3);
            gload_lds16(B + (size_t)(bcol + row) * K + k0 + c * 8,
                        bufb + ABUF + j * 4096 + tid * 16);
        }
    };

    f32x16 acc[3][2];
#pragma unroll
    for (int mi = 0; mi < 3; ++mi)
#pragma unroll
        for (int ni = 0; ni < 2; ++ni)
#pragma unroll
            for (int r = 0; r < 16; ++r) acc[mi][ni][r] = 0.f;

    // prologue: 3 K-steps in flight; drain step 0 (15 outstanding -> 10)
    stage(0); stage(1); stage(2);
    asm volatile("s_waitcnt vmcnt(10)" ::: "memory");
    asm volatile("" ::: "memory");
    __builtin_amdgcn_s_barrier();
    asm volatile("" ::: "memory");

    for (int t = 0; t < NT; ++t) {
        if (t + 3 < NT) stage(t + 3);     // into buf (t-1)&3, freed last step
        const char* ab = lds + (size_t)(t & 3) * BUFSZ;
        const char* bb = ab + ABUF;
#pragma unroll
        for (int kh = 0; kh < 2; ++kh) {  // two k=16 halves of the K-step
            f16x8 af[3], bf[2];
#pragma unroll
            for (int mi = 0; mi < 3; ++mi) {
                const int row = wm * 96 + mi * 32 + (lane & 31);
                const int c = (kh * 2 + (lane >> 5)) ^ ((row >> 1) & 3);
                af[mi] = *reinterpret_cast<const f16x8*>(ab + row * 64 + c * 16);
            }
#pragma unroll
            for (int ni = 0; ni < 2; ++ni) {
                const int row = wn * 64 + ni * 32 + (lane & 31);
                const int c = (kh * 2 + (lane >> 5)) ^ ((row >> 1) & 3);
                bf[ni] = *reinterpret_cast<const f16x8*>(bb + row * 64 + c * 16);
            }
            __builtin_amdgcn_s_setprio(1);
#pragma unroll
            for (int mi = 0; mi < 3; ++mi)
#pragma unroll
                for (int ni = 0; ni < 2; ++ni)
                    acc[mi][ni] = __builtin_amdgcn_mfma_f32_32x32x16_f16(
                        af[mi], bf[ni], acc[mi][ni], 0, 0, 0);
            __builtin_amdgcn_s_setprio(0);
        }
        // counted drain: guarantee stage(t+1) landed before next iteration
        if (t + 3 < NT)      asm volatile("s_waitcnt vmcnt(10)" ::: "memory");
        else if (t + 2 < NT) asm volatile("s_waitcnt vmcnt(5)" ::: "memory");
        else if (t + 1 < NT) asm volatile("s_waitcnt vmcnt(0)" ::: "memory");
        asm volatile("" ::: "memory");
        __builtin_amdgcn_s_barrier();
        asm volatile("" ::: "memory");
    }

    // epilogue: 32x32 C/D layout col=lane&31, row=(reg&3)+8*(reg>>2)+4*(lane>>5)
    if (SPLIT_V && bcol >= V_OFF) {
#pragma unroll
        for (int mi = 0; mi < 3; ++mi)
#pragma unroll
            for (int ni = 0; ni < 2; ++ni) {
                const int col = bcol - V_OFF + wn * 64 + ni * 32 + (lane & 31);
                const int rbase = brow + wm * 96 + mi * 32 + 4 * (lane >> 5);
#pragma unroll
                for (int r = 0; r < 16; ++r) {
                    const int row = rbase + (r & 3) + 8 * (r >> 2);
                    vt[(size_t)col * M + row] = (_Float16)acc[mi][ni][r];
                }
            }
    } else {
#pragma unroll
        for (int mi = 0; mi < 3; ++mi)
#pragma unroll
            for (int ni = 0; ni < 2; ++ni) {
                const int col = bcol + wn * 64 + ni * 32 + (lane & 31);
                const int rbase = brow + wm * 96 + mi * 32 + 4 * (lane >> 5);
#pragma unroll
                for (int r = 0; r < 16; ++r) {
                    const int row = rbase + (r & 3) + 8 * (r >> 2);
                    C[(size_t)row * N + col] = (OutT)acc[mi][ni][r];
                }
            }
    }
}

// ---------------------------------------------------------------------------
__global__ __launch_bounds__(256) void cast_f32_f16(const float* __restrict__ in,
                                                    _Float16* __restrict__ out, int n) {
    const int i = (blockIdx.x * 256 + threadIdx.x) * 8;
    if (i >= n) return;
    float4 a = *reinterpret_cast<const float4*>(&in[i]);
    float4 b = *reinterpret_cast<const float4*>(&in[i + 4]);
    f16x8 o;
    o[0] = (_Float16)a.x; o[1] = (_Float16)a.y; o[2] = (_Float16)a.z; o[3] = (_Float16)a.w;
    o[4] = (_Float16)b.x; o[5] = (_Float16)b.y; o[6] = (_Float16)b.z; o[7] = (_Float16)b.w;
    *reinterpret_cast<f16x8*>(&out[i]) = o;
}

// ---------------------------------------------------------------------------
// Fused: hs f32 -> f16 cast AND gate[t][h] = log_sigmoid(hs[t].g_w[h]).
// ---------------------------------------------------------------------------
__global__ __launch_bounds__(256) void cast_gate(const float* __restrict__ hs,
                                                 const float* __restrict__ g_w,
                                                 _Float16* __restrict__ hs16,
                                                 float* __restrict__ gate) {
    const int t = blockIdx.x;
    const int tid = threadIdx.x, lane = tid & 63, wave = tid >> 6;
    const int i = tid * 8;
    const float* row = hs + (size_t)t * HID_DIM;
    float4 a = *reinterpret_cast<const float4*>(&row[i]);
    float4 b = *reinterpret_cast<const float4*>(&row[i + 4]);
    f16x8 o;
    o[0] = (_Float16)a.x; o[1] = (_Float16)a.y; o[2] = (_Float16)a.z; o[3] = (_Float16)a.w;
    o[4] = (_Float16)b.x; o[5] = (_Float16)b.y; o[6] = (_Float16)b.z; o[7] = (_Float16)b.w;
    *reinterpret_cast<f16x8*>(&hs16[(size_t)t * HID_DIM + i]) = o;

    float s[NKV];
#pragma unroll
    for (int h = 0; h < NKV; ++h) {
        const float4 wa = *reinterpret_cast<const float4*>(&g_w[(size_t)h * HID_DIM + i]);
        const float4 wb = *reinterpret_cast<const float4*>(&g_w[(size_t)h * HID_DIM + i + 4]);
        s[h] = a.x * wa.x + a.y * wa.y + a.z * wa.z + a.w * wa.w
             + b.x * wb.x + b.y * wb.y + b.z * wb.z + b.w * wb.w;
    }
#pragma unroll
    for (int off = 32; off > 0; off >>= 1)
#pragma unroll
        for (int h = 0; h < NKV; ++h) s[h] += __shfl_down(s[h], off, 64);
    __shared__ float red[4][NKV];
    if (lane == 0)
#pragma unroll
        for (int h = 0; h < NKV; ++h) red[wave][h] = s[h];
    __syncthreads();
    if (tid < NKV) {
        float x = red[0][tid] + red[1][tid] + red[2][tid] + red[3][tid];
        float ls = fminf(x, 0.f) - log1pf(expf(-fabsf(x)));
        gate[(size_t)t * NKV + tid] = ls;
    }
}

// ---------------------------------------------------------------------------
__global__ __launch_bounds__(1024) void cumsum_kernel(const float* __restrict__ gate,
                                                      float* __restrict__ cg) {
    const int h = blockIdx.x;
    const int tid = threadIdx.x;
    float v0 = gate[(size_t)(tid * 3 + 0) * NKV + h];
    float v1 = gate[(size_t)(tid * 3 + 1) * NKV + h];
    float v2 = gate[(size_t)(tid * 3 + 2) * NKV + h];
    float p0 = v0, p1 = v0 + v1, p2 = v0 + v1 + v2;
    __shared__ float s[1024];
    s[tid] = p2;
    __syncthreads();
    float sum = p2;
    for (int off = 1; off < 1024; off <<= 1) {
        float add = (tid >= off) ? s[tid - off] : 0.f;
        __syncthreads();
        sum += add;
        s[tid] = sum;
        __syncthreads();
    }
    float base = sum - p2;
    cg[(size_t)(tid * 3 + 0) * NKV + h] = base + p0;
    cg[(size_t)(tid * 3 + 1) * NKV + h] = base + p1;
    cg[(size_t)(tid * 3 + 2) * NKV + h] = base + p2;
}

// ---------------------------------------------------------------------------
__global__ __launch_bounds__(128) void norm_rope_kernel(_Float16* __restrict__ qkv,
                                                        const float* __restrict__ qw,
                                                        const float* __restrict__ kw,
                                                        const int* __restrict__ positions) {
    const int t = blockIdx.x;
    const int head = blockIdx.y;  // 0..23
    const int d = threadIdx.x;
    const bool is_q = head < NH;
    _Float16* row = qkv + (size_t)t * QKV_COLS + (is_q ? head * HD : NH * HD + (head - NH) * HD);
    float x = (float)row[d];
    float ss = x * x;
#pragma unroll
    for (int off = 32; off > 0; off >>= 1) ss += __shfl_down(ss, off, 64);
    __shared__ float r2[2];
    __shared__ float vals[HD];
    if ((threadIdx.x & 63) == 0) r2[threadIdx.x >> 6] = ss;
    __syncthreads();
    float var = (r2[0] + r2[1]) * (1.0f / HD);
    float rs = rsqrtf(var + RMS_EPS);
    const float* w = is_q ? qw : kw;
    float v = x * rs * w[d];
    vals[d] = v;
    __syncthreads();
    const int i = d & 63;
    float inv_freq = powf(THETA, -(float)i * (1.0f / 64.0f));
    float ang = (float)positions[t] * inv_freq;
    float sn, cs;
    sincosf(ang, &sn, &cs);
    float out;
    if (d < 64) out = v * cs - vals[d + 64] * sn;
    else        out = v * cs + vals[d - 64] * sn;
    if (is_q) out *= SCALE;
    row[d] = (_Float16)out;
}

// ---------------------------------------------------------------------------
// Pipelined MFMA banded retention (verified round 6, unchanged).
// ---------------------------------------------------------------------------
__global__ __launch_bounds__(256, 2) void attn_mfma2(const _Float16* __restrict__ qkv,
                                                     const _Float16* __restrict__ vt,
                                                     const float* __restrict__ cg,
                                                     _Float16* __restrict__ out) {
    const int h = blockIdx.y;             // kv head 0..7
    const int t0 = blockIdx.x * AQT;
    const int tid = threadIdx.x, lane = tid & 63, wid = tid >> 6;

    __shared__ char buf[4][16384];        // per buffer: Ks[32][128] 8KB | Vs[128][32] 8KB
    __shared__ char WsB[2][4096];         // per-head W tile [64][32], wave-private rows
    __shared__ float cgS[BAND + AQT];     // band cumsum slice

    const int s_lo = (t0 >= BAND) ? t0 - BAND : 0;
    const int NT = (t0 + AQT - s_lo) >> 5;
    const int span = t0 + AQT - s_lo;

    for (int i = tid; i < span; i += 256)
        cgS[i] = cg[(size_t)(s_lo + i) * NKV + h];

    f16x8 qa[2][4];
    {
        const int qrow = t0 + wid * 16 + (lane & 15);
#pragma unroll
        for (int hh = 0; hh < 2; ++hh) {
            const _Float16* qp = qkv + (size_t)qrow * QKV_COLS + (2 * h + hh) * HD + (lane >> 4) * 8;
#pragma unroll
            for (int kq = 0; kq < 4; ++kq)
                qa[hh][kq] = *reinterpret_cast<const f16x8*>(qp + kq * 32);
        }
    }

    auto stage = [&](int t) {
        const int s0 = s_lo + t * 32;
        char* kd = (char*)buf + (size_t)(t & 3) * 16384;
        char* vd = kd + 8192;
#pragma unroll
        for (int i = 0; i < 2; ++i) {
            const int r = i * 16 + (tid >> 4);
            const int celem = (((tid & 15) * 16) ^ ((r & 7) << 4)) >> 1;
            gload_lds16(qkv + (size_t)(s0 + r) * QKV_COLS + NH * HD + h * HD + celem,
                        kd + i * 4096 + tid * 16);
        }
#pragma unroll
        for (int i = 0; i < 2; ++i) {
            const int d = i * 64 + (tid >> 2);
            const int key = (d ^ (d >> 2)) & 3;
            gload_lds16(vt + (size_t)(h * HD + d) * T_LEN + s0 + 8 * ((tid & 3) ^ key),
                        vd + i * 4096 + tid * 16);
        }
    };

    stage(0); stage(1); stage(2);
    __syncthreads();

    float cqr[4];
#pragma unroll
    for (int j = 0; j < 4; ++j)
        cqr[j] = cgS[(span - AQT) + wid * 16 + (lane >> 4) * 4 + j];

    f32x4 acc_o[2][8];
#pragma unroll
    for (int hh = 0; hh < 2; ++hh)
#pragma unroll
        for (int nq = 0; nq < 8; ++nq) acc_o[hh][nq] = (f32x4){0.f, 0.f, 0.f, 0.f};
    float dsum[2][4] = {{0.f, 0.f, 0.f, 0.f}, {0.f, 0.f, 0.f, 0.f}};

    for (int t = 0; t < NT; ++t) {
        if (t + 3 < NT) stage(t + 3);
        const char* kbase = (const char*)buf + (size_t)(t & 3) * 16384;
        const char* vbase = kbase + 8192;
        const int s0 = s_lo + t * 32;

        f16x8 kf[2][4];
#pragma unroll
        for (int c = 0; c < 2; ++c) {
            const int rr = c * 16 + (lane & 15);
#pragma unroll
            for (int kq = 0; kq < 4; ++kq) {
                const int bi = (kq * 64 + (lane >> 4) * 16) ^ ((rr & 7) << 4);
                kf[c][kq] = *reinterpret_cast<const f16x8*>(kbase + rr * 256 + bi);
            }
        }
        float csv[2];
        csv[0] = cgS[t * 32 + (lane & 15)];
        csv[1] = cgS[t * 32 + 16 + (lane & 15)];

#pragma unroll
        for (int hh = 0; hh < 2; ++hh) {
            f32x4 accs[2];
            accs[0] = (f32x4){0.f, 0.f, 0.f, 0.f};
            accs[1] = (f32x4){0.f, 0.f, 0.f, 0.f};
#pragma unroll
            for (int c = 0; c < 2; ++c)
#pragma unroll
                for (int kq = 0; kq < 4; ++kq)
                    accs[c] = __builtin_amdgcn_mfma_f32_16x16x32_f16(
                        qa[hh][kq], kf[c][kq], accs[c], 0, 0, 0);
#pragma unroll
            for (int c = 0; c < 2; ++c) {
                const int sg = s0 + c * 16 + (lane & 15);
#pragma unroll
                for (int j = 0; j < 4; ++j) {
                    const int qg = t0 + wid * 16 + (lane >> 4) * 4 + j;
                    const float sv = accs[c][j];
                    const float w = (sg <= qg) ? __expf(cqr[j] - csv[c]) * sv * sv : 0.f;
                    const _Float16 wh = (_Float16)w;
                    dsum[hh][j] += (float)wh;
                    const int q = wid * 16 + (lane >> 4) * 4 + j;
                    const int addr = q * 64 +
                        ((2 * (c * 16 + (lane & 15))) ^ (((q ^ (q >> 2)) & 3) << 4));
                    *(_Float16*)(WsB[hh] + addr) = wh;
                }
            }
        }
        asm volatile("s_waitcnt lgkmcnt(0)" ::: "memory");
    __builtin_amdgcn_sched_barrier(0);

        const int qr = wid * 16 + (lane & 15);
        const int wb = qr * 64 + (((lane >> 4) * 16) ^ (((qr ^ (qr >> 2)) & 3) << 4));
        f16x8 wf0 = *reinterpret_cast<const f16x8*>(WsB[0] + wb);
        f16x8 wf1 = *reinterpret_cast<const f16x8*>(WsB[1] + wb);
        f16x8 vf[8];
#pragma unroll
        for (int nq = 0; nq < 8; ++nq) {
            const int dr = nq * 16 + (lane & 15);
            const int vb = dr * 64 + (((lane >> 4) * 16) ^ (((dr ^ (dr >> 2)) & 3) << 4));
            vf[nq] = *reinterpret_cast<const f16x8*>(vbase + vb);
        }
        __builtin_amdgcn_s_setprio(1);
#pragma unroll
        for (int nq = 0; nq < 8; ++nq) {
            acc_o[0][nq] = __builtin_amdgcn_mfma_f32_16x16x32_f16(wf0, vf[nq], acc_o[0][nq], 0, 0, 0);
            acc_o[1][nq] = __builtin_amdgcn_mfma_f32_16x16x32_f16(wf1, vf[nq], acc_o[1][nq], 0, 0, 0);
        }
        __builtin_amdgcn_s_setprio(0);

        const int rem = NT - 1 - t;
        if (rem >= 3)      asm volatile("s_waitcnt vmcnt(8)" ::: "memory");
        else if (rem == 2) asm volatile("s_waitcnt vmcnt(4)" ::: "memory");
        else if (rem == 1) asm volatile("s_waitcnt vmcnt(0)" ::: "memory");
        asm volatile("" ::: "memory");
        if (rem > 0) __builtin_amdgcn_s_barrier();
        asm volatile("" ::: "memory");
    }

#pragma unroll
    for (int hh = 0; hh < 2; ++hh) {
        float inv[4];
#pragma unroll
        for (int j = 0; j < 4; ++j) {
            float d = dsum[hh][j];
            d += __shfl_xor(d, 1, 64);
            d += __shfl_xor(d, 2, 64);
            d += __shfl_xor(d, 4, 64);
            d += __shfl_xor(d, 8, 64);
            inv[j] = 1.f / (d + NORM_EPS);
        }
#pragma unroll
        for (int nq = 0; nq < 8; ++nq)
#pragma unroll
            for (int j = 0; j < 4; ++j) {
                const int row = t0 + wid * 16 + (lane >> 4) * 4 + j;
                out[(size_t)row * (NH * HD) + (2 * h + hh) * HD + nq * 16 + (lane & 15)] =
                    (_Float16)(acc_o[hh][nq][j] * inv[j]);
            }
    }
}

// ---------------------------------------------------------------------------
extern "C" void kernel_launch(void* const* d_in, const int* in_sizes, int n_in,
                              void* d_out, int out_size, void* d_ws, size_t ws_size,
                              hipStream_t stream) {
    const float* hs    = (const float*)d_in[0];
    const float* qkv_w = (const float*)d_in[1];
    const float* g_w   = (const float*)d_in[2];
    const float* o_w   = (const float*)d_in[3];
    const float* q_nw  = (const float*)d_in[4];
    const float* k_nw  = (const float*)d_in[5];
    const int*   pos   = (const int*)d_in[6];

    _Float16* hs16   = (_Float16*)d_ws;                      // 3072*2048 (reused for attn out)
    _Float16* qkvw16 = hs16 + (size_t)T_LEN * HID_DIM;       // 4096*2048
    _Float16* ow16   = qkvw16 + (size_t)QKV_COLS * HID_DIM;  // 2048*2048
    _Float16* qkv16  = ow16 + (size_t)HID_DIM * HID_DIM;     // 3072*4096 (v region unused)
    _Float16* vtb    = qkv16 + (size_t)T_LEN * QKV_COLS;     // 1024*3072 (V transposed)
    float* gate = (float*)(vtb + (size_t)NKV * HD * T_LEN);
    float* cgb  = gate + (size_t)T_LEN * NKV;

    cast_gate<<<T_LEN, 256, 0, stream>>>(hs, g_w, hs16, gate);
    cast_f32_f16<<<(QKV_COLS * HID_DIM) / 2048, 256, 0, stream>>>(qkv_w, qkvw16, QKV_COLS * HID_DIM);
    cast_f32_f16<<<(HID_DIM * HID_DIM) / 2048, 256, 0, stream>>>(o_w, ow16, HID_DIM * HID_DIM);
    cumsum_kernel<<<NKV, 1024, 0, stream>>>(gate, cgb);
    // qkv projection: 192x128 tiles, 16x32 = 512 blocks (2/CU); v transposed
    gemm_192<T_LEN, QKV_COLS, HID_DIM, _Float16, true>
        <<<(T_LEN / 192) * (QKV_COLS / 128), 256, 0, stream>>>(hs16, qkvw16, qkv16, vtb);
    norm_rope_kernel<<<dim3(T_LEN, NH + NKV), 128, 0, stream>>>(qkv16, q_nw, k_nw, pos);
    // pipelined retention: 48 x 8 blocks, 2 q-heads per block
    attn_mfma2<<<dim3(T_LEN / AQT, NKV), 256, 0, stream>>>(qkv16, vtb, cgb, hs16);
    // output projection: 192x128 tiles, 16x16 = 256 blocks
    gemm_192<T_LEN, HID_DIM, HID_DIM, float, false>
        <<<(T_LEN / 192) * (HID_DIM / 128), 256, 0, stream>>>(hs16, ow16, (float*)d_out, nullptr);
    (void)in_sizes; (void)n_in; (void)out_size; (void)ws_size;
}

// Round 9
// 206.107 us; speedup vs baseline: 1.0598x; 1.0598x over previous
//
#include <hip/hip_runtime.h>
#include <math.h>

#define T_LEN 3072
#define HID_DIM 2048
#define NH 16
#define NKV 8
#define HD 128
#define QKV_COLS ((NH + 2 * NKV) * HD)   // 4096
#define V_OFF (NH * HD + NKV * HD)       // 3072
#define RMS_EPS 1e-6f
#define NORM_EPS 1e-6f
#define THETA 10000.0f
#define SCALE 0.08838834764831845f       // 128^-0.5

#define BAND 256   // exp(-0.65*256)=e^-167 -> exactly 0 in f32; validated round 1
#define AQT 64     // q rows per attn block

typedef __attribute__((ext_vector_type(8))) _Float16 f16x8;
typedef __attribute__((ext_vector_type(4))) float f32x4;

__device__ __forceinline__ void gload_lds16(const void* g, void* l) {
    __builtin_amdgcn_global_load_lds((const __attribute__((address_space(1))) void*)g,
                                     (__attribute__((address_space(3))) void*)l, 16, 0, 0);
}
__device__ __forceinline__ void gload_lds4(const void* g, void* l) {
    __builtin_amdgcn_global_load_lds((const __attribute__((address_space(1))) void*)g,
                                     (__attribute__((address_space(3))) void*)l, 4, 0, 0);
}

#define VMCNT_I(n) asm volatile("s_waitcnt vmcnt(" #n ")" ::: "memory")

// ---------------------------------------------------------------------------
// m201-granularity f16 MFMA GEMM: C[M][N] = A[M][K] @ B[N][K]^T, f32 acc.
// BK=64 (2 halves), double-buffered LDS, 8 waves (WMxWN), per half NGROUP
// phases of {ds_read (3 af + 4 bf at g0) || stage half of t+1 -> barrier ->
// lgkmcnt(0)+sched_barrier -> setprio + 12 MFMA -> [vmcnt(NISS) at half
// boundary] -> barrier}. 64B LDS rows, chunk swizzle c^((row>>1)&3)
// (2-way = free; 0 conflicts measured r5/r7). Full-machine 256-block grids.
// Remainder staging uses 2x width-4 gload so every wave's vmcnt count is
// identical (counted-wait correctness).
// SPLIT_V: blocks with bcol >= V_OFF write transposed into vt.
// ---------------------------------------------------------------------------
template <int M, int N, int K, int BM, int BN, int WM, int WN, int WPE,
          typename OutT, bool SPLIT_V>
__global__ __launch_bounds__(512, WPE) void gemm_mph(const _Float16* __restrict__ A,
                                                     const _Float16* __restrict__ Bp,
                                                     OutT* __restrict__ C,
                                                     _Float16* __restrict__ vt) {
    constexpr int MI = BM / WM / 16;
    constexpr int NGROUP = (MI >= 6) ? 2 : 1;
    constexpr int GSZ = MI / NGROUP;          // 3
    constexpr int NI = BN / WN / 16;          // 4
    constexpr int NT = K / 64;
    constexpr int NX = N / BN;
    constexpr int HALF = (BM + BN) * 64;      // bytes per K-half (A rows | B rows)
    constexpr int FULL = HALF / 8192;         // full 16B staging issues
    constexpr int REM = HALF - FULL * 8192;   // 0 or 4096
    constexpr int NISS = FULL + (REM ? 2 : 0);
    static_assert(REM == 0 || REM == 4096, "staging remainder must be 4KB");
    __shared__ char lds[2 * 2 * HALF];

    const int tid = threadIdx.x, lane = tid & 63, wid = tid >> 6;
    const int wm = wid / WN, wn = wid % WN;
    const int q8 = gridDim.x >> 3;
    const int sw = (blockIdx.x & 7) * q8 + (blockIdx.x >> 3);
    const int brow = (sw / NX) * BM, bcol = (sw % NX) * BN;

    auto stage_half = [&](int t, int kh) {
        char* hb = lds + (size_t)((t & 1) * 2 + kh) * HALF;
        const int k0 = t * 64 + kh * 32;
#pragma unroll
        for (int j = 0; j < FULL; ++j) {
            const int L = j * 8192 + tid * 16;
            if (L < BM * 64) {
                const int r = L >> 6;
                const int c = ((L >> 4) & 3) ^ ((r >> 1) & 3);
                gload_lds16(A + (size_t)(brow + r) * K + k0 + c * 8, hb + L);
            } else {
                const int Lb = L - BM * 64;
                const int r = Lb >> 6;
                const int c = ((Lb >> 4) & 3) ^ ((r >> 1) & 3);
                gload_lds16(Bp + (size_t)(bcol + r) * K + k0 + c * 8, hb + L);
            }
        }
        if constexpr (REM != 0) {
            // 4KB remainder (all-B region): 2 width-4 issues, all 512 threads
            // -> per-wave vmem count stays uniform across the block.
#pragma unroll
            for (int j = 0; j < 2; ++j) {
                const int L = FULL * 8192 + j * 2048 + (tid >> 6) * 256 + (tid & 63) * 4;
                const int Lb = L - BM * 64;
                const int r = Lb >> 6;
                const int wb = Lb & 63;
                const int c = (wb >> 4) ^ ((r >> 1) & 3);
                gload_lds4(Bp + (size_t)(bcol + r) * K + k0 + c * 8 + ((wb & 15) >> 1),
                           hb + (L & ~255));   // wave-uniform base; HW adds lane*4
            }
        }
    };
    auto wait_n = [&]() {
        if constexpr (NISS == 5) VMCNT_I(5);
        else if constexpr (NISS == 4) VMCNT_I(4);
        else VMCNT_I(3);
    };

    f32x4 acc[MI][NI];
#pragma unroll
    for (int mi = 0; mi < MI; ++mi)
#pragma unroll
        for (int ni = 0; ni < NI; ++ni) acc[mi][ni] = (f32x4){0.f, 0.f, 0.f, 0.f};

    // prologue: stage tile 0 both halves; guarantee h0 landed (oldest NISS)
    stage_half(0, 0);
    stage_half(0, 1);
    wait_n();
    asm volatile("" ::: "memory");
    __builtin_amdgcn_s_barrier();
    asm volatile("" ::: "memory");

    for (int t = 0; t < NT; ++t) {
        const char* buf = lds + (size_t)(t & 1) * 2 * HALF;
#pragma unroll
        for (int kh = 0; kh < 2; ++kh) {
            const char* ab = buf + kh * HALF;
            const char* bb = ab + BM * 64;
            f16x8 bf[NI];
#pragma unroll
            for (int g = 0; g < NGROUP; ++g) {
                if (g == 0) {
#pragma unroll
                    for (int ni = 0; ni < NI; ++ni) {
                        const int r = wn * (BN / WN) + ni * 16 + (lane & 15);
                        bf[ni] = *reinterpret_cast<const f16x8*>(
                            bb + r * 64 + ((((lane >> 4)) ^ ((r >> 1) & 3)) << 4));
                    }
                }
                f16x8 af[GSZ];
#pragma unroll
                for (int m = 0; m < GSZ; ++m) {
                    const int r = wm * (BM / WM) + (g * GSZ + m) * 16 + (lane & 15);
                    af[m] = *reinterpret_cast<const f16x8*>(
                        ab + r * 64 + ((((lane >> 4)) ^ ((r >> 1) & 3)) << 4));
                }
                if (g == 0 && t + 1 < NT) stage_half(t + 1, kh);
                asm volatile("" ::: "memory");
                __builtin_amdgcn_s_barrier();
                asm volatile("s_waitcnt lgkmcnt(0)" ::: "memory");
                __builtin_amdgcn_sched_barrier(0);
                __builtin_amdgcn_s_setprio(1);
#pragma unroll
                for (int m = 0; m < GSZ; ++m)
#pragma unroll
                    for (int ni = 0; ni < NI; ++ni)
                        acc[g * GSZ + m][ni] = __builtin_amdgcn_mfma_f32_16x16x32_f16(
                            af[m], bf[ni], acc[g * GSZ + m][ni], 0, 0, 0);
                __builtin_amdgcn_s_setprio(0);
                if (g == NGROUP - 1) {
                    if (kh == 0) {
                        if (t == NT - 1) VMCNT_I(0);   // tail: drain leftover h1
                        else wait_n();                 // guard t h1
                    } else if (t + 1 < NT) {
                        wait_n();                      // guard t+1 h0
                    }
                }
                asm volatile("" ::: "memory");
                __builtin_amdgcn_s_barrier();
                asm volatile("" ::: "memory");
            }
        }
    }

    // epilogue: 16x16 C/D layout col=lane&15, row=(lane>>4)*4+j (validated)
    if (SPLIT_V && bcol >= V_OFF) {
#pragma unroll
        for (int mi = 0; mi < MI; ++mi)
#pragma unroll
            for (int ni = 0; ni < NI; ++ni) {
                const int col = bcol - V_OFF + wn * (BN / WN) + ni * 16 + (lane & 15);
                const int rb = brow + wm * (BM / WM) + mi * 16 + (lane >> 4) * 4;
#pragma unroll
                for (int j = 0; j < 4; ++j)
                    vt[(size_t)col * M + rb + j] = (_Float16)acc[mi][ni][j];
            }
    } else {
#pragma unroll
        for (int mi = 0; mi < MI; ++mi)
#pragma unroll
            for (int ni = 0; ni < NI; ++ni) {
                const int col = bcol + wn * (BN / WN) + ni * 16 + (lane & 15);
                const int rb = brow + wm * (BM / WM) + mi * 16 + (lane >> 4) * 4;
#pragma unroll
                for (int j = 0; j < 4; ++j)
                    C[(size_t)(rb + j) * N + col] = (OutT)acc[mi][ni][j];
            }
    }
}

// ---------------------------------------------------------------------------
__global__ __launch_bounds__(256) void cast_f32_f16(const float* __restrict__ in,
                                                    _Float16* __restrict__ out, int n) {
    const int i = (blockIdx.x * 256 + threadIdx.x) * 8;
    if (i >= n) return;
    float4 a = *reinterpret_cast<const float4*>(&in[i]);
    float4 b = *reinterpret_cast<const float4*>(&in[i + 4]);
    f16x8 o;
    o[0] = (_Float16)a.x; o[1] = (_Float16)a.y; o[2] = (_Float16)a.z; o[3] = (_Float16)a.w;
    o[4] = (_Float16)b.x; o[5] = (_Float16)b.y; o[6] = (_Float16)b.z; o[7] = (_Float16)b.w;
    *reinterpret_cast<f16x8*>(&out[i]) = o;
}

// ---------------------------------------------------------------------------
// Fused: hs f32 -> f16 cast AND gate[t][h] = log_sigmoid(hs[t].g_w[h]).
// ---------------------------------------------------------------------------
__global__ __launch_bounds__(256) void cast_gate(const float* __restrict__ hs,
                                                 const float* __restrict__ g_w,
                                                 _Float16* __restrict__ hs16,
                                                 float* __restrict__ gate) {
    const int t = blockIdx.x;
    const int tid = threadIdx.x, lane = tid & 63, wave = tid >> 6;
    const int i = tid * 8;
    const float* row = hs + (size_t)t * HID_DIM;
    float4 a = *reinterpret_cast<const float4*>(&row[i]);
    float4 b = *reinterpret_cast<const float4*>(&row[i + 4]);
    f16x8 o;
    o[0] = (_Float16)a.x; o[1] = (_Float16)a.y; o[2] = (_Float16)a.z; o[3] = (_Float16)a.w;
    o[4] = (_Float16)b.x; o[5] = (_Float16)b.y; o[6] = (_Float16)b.z; o[7] = (_Float16)b.w;
    *reinterpret_cast<f16x8*>(&hs16[(size_t)t * HID_DIM + i]) = o;

    float s[NKV];
#pragma unroll
    for (int h = 0; h < NKV; ++h) {
        const float4 wa = *reinterpret_cast<const float4*>(&g_w[(size_t)h * HID_DIM + i]);
        const float4 wb = *reinterpret_cast<const float4*>(&g_w[(size_t)h * HID_DIM + i + 4]);
        s[h] = a.x * wa.x + a.y * wa.y + a.z * wa.z + a.w * wa.w
             + b.x * wb.x + b.y * wb.y + b.z * wb.z + b.w * wb.w;
    }
#pragma unroll
    for (int off = 32; off > 0; off >>= 1)
#pragma unroll
        for (int h = 0; h < NKV; ++h) s[h] += __shfl_down(s[h], off, 64);
    __shared__ float red[4][NKV];
    if (lane == 0)
#pragma unroll
        for (int h = 0; h < NKV; ++h) red[wave][h] = s[h];
    __syncthreads();
    if (tid < NKV) {
        float x = red[0][tid] + red[1][tid] + red[2][tid] + red[3][tid];
        float ls = fminf(x, 0.f) - log1pf(expf(-fabsf(x)));
        gate[(size_t)t * NKV + tid] = ls;
    }
}

// ---------------------------------------------------------------------------
__global__ __launch_bounds__(1024) void cumsum_kernel(const float* __restrict__ gate,
                                                      float* __restrict__ cg) {
    const int h = blockIdx.x;
    const int tid = threadIdx.x;
    float v0 = gate[(size_t)(tid * 3 + 0) * NKV + h];
    float v1 = gate[(size_t)(tid * 3 + 1) * NKV + h];
    float v2 = gate[(size_t)(tid * 3 + 2) * NKV + h];
    float p0 = v0, p1 = v0 + v1, p2 = v0 + v1 + v2;
    __shared__ float s[1024];
    s[tid] = p2;
    __syncthreads();
    float sum = p2;
    for (int off = 1; off < 1024; off <<= 1) {
        float add = (tid >= off) ? s[tid - off] : 0.f;
        __syncthreads();
        sum += add;
        s[tid] = sum;
        __syncthreads();
    }
    float base = sum - p2;
    cg[(size_t)(tid * 3 + 0) * NKV + h] = base + p0;
    cg[(size_t)(tid * 3 + 1) * NKV + h] = base + p1;
    cg[(size_t)(tid * 3 + 2) * NKV + h] = base + p2;
}

// ---------------------------------------------------------------------------
__global__ __launch_bounds__(128) void norm_rope_kernel(_Float16* __restrict__ qkv,
                                                        const float* __restrict__ qw,
                                                        const float* __restrict__ kw,
                                                        const int* __restrict__ positions) {
    const int t = blockIdx.x;
    const int head = blockIdx.y;  // 0..23
    const int d = threadIdx.x;
    const bool is_q = head < NH;
    _Float16* row = qkv + (size_t)t * QKV_COLS + (is_q ? head * HD : NH * HD + (head - NH) * HD);
    float x = (float)row[d];
    float ss = x * x;
#pragma unroll
    for (int off = 32; off > 0; off >>= 1) ss += __shfl_down(ss, off, 64);
    __shared__ float r2[2];
    __shared__ float vals[HD];
    if ((threadIdx.x & 63) == 0) r2[threadIdx.x >> 6] = ss;
    __syncthreads();
    float var = (r2[0] + r2[1]) * (1.0f / HD);
    float rs = rsqrtf(var + RMS_EPS);
    const float* w = is_q ? qw : kw;
    float v = x * rs * w[d];
    vals[d] = v;
    __syncthreads();
    const int i = d & 63;
    float inv_freq = powf(THETA, -(float)i * (1.0f / 64.0f));
    float ang = (float)positions[t] * inv_freq;
    float sn, cs;
    sincosf(ang, &sn, &cs);
    float out;
    if (d < 64) out = v * cs - vals[d + 64] * sn;
    else        out = v * cs + vals[d - 64] * sn;
    if (is_q) out *= SCALE;
    row[d] = (_Float16)out;
}

// ---------------------------------------------------------------------------
// Pipelined MFMA banded retention (verified round 6, unchanged).
// ---------------------------------------------------------------------------
__global__ __launch_bounds__(256, 2) void attn_mfma2(const _Float16* __restrict__ qkv,
                                                     const _Float16* __restrict__ vt,
                                                     const float* __restrict__ cg,
                                                     _Float16* __restrict__ out) {
    const int h = blockIdx.y;             // kv head 0..7
    const int t0 = blockIdx.x * AQT;
    const int tid = threadIdx.x, lane = tid & 63, wid = tid >> 6;

    __shared__ char buf[4][16384];        // per buffer: Ks[32][128] 8KB | Vs[128][32] 8KB
    __shared__ char WsB[2][4096];         // per-head W tile [64][32], wave-private rows
    __shared__ float cgS[BAND + AQT];     // band cumsum slice

    const int s_lo = (t0 >= BAND) ? t0 - BAND : 0;
    const int NT = (t0 + AQT - s_lo) >> 5;
    const int span = t0 + AQT - s_lo;

    for (int i = tid; i < span; i += 256)
        cgS[i] = cg[(size_t)(s_lo + i) * NKV + h];

    f16x8 qa[2][4];
    {
        const int qrow = t0 + wid * 16 + (lane & 15);
#pragma unroll
        for (int hh = 0; hh < 2; ++hh) {
            const _Float16* qp = qkv + (size_t)qrow * QKV_COLS + (2 * h + hh) * HD + (lane >> 4) * 8;
#pragma unroll
            for (int kq = 0; kq < 4; ++kq)
                qa[hh][kq] = *reinterpret_cast<const f16x8*>(qp + kq * 32);
        }
    }

    auto stage = [&](int t) {
        const int s0 = s_lo + t * 32;
        char* kd = (char*)buf + (size_t)(t & 3) * 16384;
        char* vd = kd + 8192;
#pragma unroll
        for (int i = 0; i < 2; ++i) {
            const int r = i * 16 + (tid >> 4);
            const int celem = (((tid & 15) * 16) ^ ((r & 7) << 4)) >> 1;
            gload_lds16(qkv + (size_t)(s0 + r) * QKV_COLS + NH * HD + h * HD + celem,
                        kd + i * 4096 + tid * 16);
        }
#pragma unroll
        for (int i = 0; i < 2; ++i) {
            const int d = i * 64 + (tid >> 2);
            const int key = (d ^ (d >> 2)) & 3;
            gload_lds16(vt + (size_t)(h * HD + d) * T_LEN + s0 + 8 * ((tid & 3) ^ key),
                        vd + i * 4096 + tid * 16);
        }
    };

    stage(0); stage(1); stage(2);
    __syncthreads();

    float cqr[4];
#pragma unroll
    for (int j = 0; j < 4; ++j)
        cqr[j] = cgS[(span - AQT) + wid * 16 + (lane >> 4) * 4 + j];

    f32x4 acc_o[2][8];
#pragma unroll
    for (int hh = 0; hh < 2; ++hh)
#pragma unroll
        for (int nq = 0; nq < 8; ++nq) acc_o[hh][nq] = (f32x4){0.f, 0.f, 0.f, 0.f};
    float dsum[2][4] = {{0.f, 0.f, 0.f, 0.f}, {0.f, 0.f, 0.f, 0.f}};

    for (int t = 0; t < NT; ++t) {
        if (t + 3 < NT) stage(t + 3);
        const char* kbase = (const char*)buf + (size_t)(t & 3) * 16384;
        const char* vbase = kbase + 8192;
        const int s0 = s_lo + t * 32;

        f16x8 kf[2][4];
#pragma unroll
        for (int c = 0; c < 2; ++c) {
            const int rr = c * 16 + (lane & 15);
#pragma unroll
            for (int kq = 0; kq < 4; ++kq) {
                const int bi = (kq * 64 + (lane >> 4) * 16) ^ ((rr & 7) << 4);
                kf[c][kq] = *reinterpret_cast<const f16x8*>(kbase + rr * 256 + bi);
            }
        }
        float csv[2];
        csv[0] = cgS[t * 32 + (lane & 15)];
        csv[1] = cgS[t * 32 + 16 + (lane & 15)];

#pragma unroll
        for (int hh = 0; hh < 2; ++hh) {
            f32x4 accs[2];
            accs[0] = (f32x4){0.f, 0.f, 0.f, 0.f};
            accs[1] = (f32x4){0.f, 0.f, 0.f, 0.f};
#pragma unroll
            for (int c = 0; c < 2; ++c)
#pragma unroll
                for (int kq = 0; kq < 4; ++kq)
                    accs[c] = __builtin_amdgcn_mfma_f32_16x16x32_f16(
                        qa[hh][kq], kf[c][kq], accs[c], 0, 0, 0);
#pragma unroll
            for (int c = 0; c < 2; ++c) {
                const int sg = s0 + c * 16 + (lane & 15);
#pragma unroll
                for (int j = 0; j < 4; ++j) {
                    const int qg = t0 + wid * 16 + (lane >> 4) * 4 + j;
                    const float sv = accs[c][j];
                    const float w = (sg <= qg) ? __expf(cqr[j] - csv[c]) * sv * sv : 0.f;
                    const _Float16 wh = (_Float16)w;
                    dsum[hh][j] += (float)wh;
                    const int q = wid * 16 + (lane >> 4) * 4 + j;
                    const int addr = q * 64 +
                        ((2 * (c * 16 + (lane & 15))) ^ (((q ^ (q >> 2)) & 3) << 4));
                    *(_Float16*)(WsB[hh] + addr) = wh;
                }
            }
        }
        asm volatile("s_waitcnt lgkmcnt(0)" ::: "memory");
        __builtin_amdgcn_sched_barrier(0);

        const int qr = wid * 16 + (lane & 15);
        const int wb = qr * 64 + (((lane >> 4) * 16) ^ (((qr ^ (qr >> 2)) & 3) << 4));
        f16x8 wf0 = *reinterpret_cast<const f16x8*>(WsB[0] + wb);
        f16x8 wf1 = *reinterpret_cast<const f16x8*>(WsB[1] + wb);
        f16x8 vf[8];
#pragma unroll
        for (int nq = 0; nq < 8; ++nq) {
            const int dr = nq * 16 + (lane & 15);
            const int vb = dr * 64 + (((lane >> 4) * 16) ^ (((dr ^ (dr >> 2)) & 3) << 4));
            vf[nq] = *reinterpret_cast<const f16x8*>(vbase + vb);
        }
        __builtin_amdgcn_s_setprio(1);
#pragma unroll
        for (int nq = 0; nq < 8; ++nq) {
            acc_o[0][nq] = __builtin_amdgcn_mfma_f32_16x16x32_f16(wf0, vf[nq], acc_o[0][nq], 0, 0, 0);
            acc_o[1][nq] = __builtin_amdgcn_mfma_f32_16x16x32_f16(wf1, vf[nq], acc_o[1][nq], 0, 0, 0);
        }
        __builtin_amdgcn_s_setprio(0);

        const int rem = NT - 1 - t;
        if (rem >= 3)      asm volatile("s_waitcnt vmcnt(8)" ::: "memory");
        else if (rem == 2) asm volatile("s_waitcnt vmcnt(4)" ::: "memory");
        else if (rem == 1) asm volatile("s_waitcnt vmcnt(0)" ::: "memory");
        asm volatile("" ::: "memory");
        if (rem > 0) __builtin_amdgcn_s_barrier();
        asm volatile("" ::: "memory");
    }

#pragma unroll
    for (int hh = 0; hh < 2; ++hh) {
        float inv[4];
#pragma unroll
        for (int j = 0; j < 4; ++j) {
            float d = dsum[hh][j];
            d += __shfl_xor(d, 1, 64);
            d += __shfl_xor(d, 2, 64);
            d += __shfl_xor(d, 4, 64);
            d += __shfl_xor(d, 8, 64);
            inv[j] = 1.f / (d + NORM_EPS);
        }
#pragma unroll
        for (int nq = 0; nq < 8; ++nq)
#pragma unroll
            for (int j = 0; j < 4; ++j) {
                const int row = t0 + wid * 16 + (lane >> 4) * 4 + j;
                out[(size_t)row * (NH * HD) + (2 * h + hh) * HD + nq * 16 + (lane & 15)] =
                    (_Float16)(acc_o[hh][nq][j] * inv[j]);
            }
    }
}

// ---------------------------------------------------------------------------
extern "C" void kernel_launch(void* const* d_in, const int* in_sizes, int n_in,
                              void* d_out, int out_size, void* d_ws, size_t ws_size,
                              hipStream_t stream) {
    const float* hs    = (const float*)d_in[0];
    const float* qkv_w = (const float*)d_in[1];
    const float* g_w   = (const float*)d_in[2];
    const float* o_w   = (const float*)d_in[3];
    const float* q_nw  = (const float*)d_in[4];
    const float* k_nw  = (const float*)d_in[5];
    const int*   pos   = (const int*)d_in[6];

    _Float16* hs16   = (_Float16*)d_ws;                      // 3072*2048 (reused for attn out)
    _Float16* qkvw16 = hs16 + (size_t)T_LEN * HID_DIM;       // 4096*2048
    _Float16* ow16   = qkvw16 + (size_t)QKV_COLS * HID_DIM;  // 2048*2048
    _Float16* qkv16  = ow16 + (size_t)HID_DIM * HID_DIM;     // 3072*4096 (v region unused)
    _Float16* vtb    = qkv16 + (size_t)T_LEN * QKV_COLS;     // 1024*3072 (V transposed)
    float* gate = (float*)(vtb + (size_t)NKV * HD * T_LEN);
    float* cgb  = gate + (size_t)T_LEN * NKV;

    cast_gate<<<T_LEN, 256, 0, stream>>>(hs, g_w, hs16, gate);
    cast_f32_f16<<<(QKV_COLS * HID_DIM) / 2048, 256, 0, stream>>>(qkv_w, qkvw16, QKV_COLS * HID_DIM);
    cast_f32_f16<<<(HID_DIM * HID_DIM) / 2048, 256, 0, stream>>>(o_w, ow16, HID_DIM * HID_DIM);
    cumsum_kernel<<<NKV, 1024, 0, stream>>>(gate, cgb);
    // qkv projection: 192x256 tiles, 16x16 = 256 blocks (full machine)
    gemm_mph<T_LEN, QKV_COLS, HID_DIM, 192, 256, 2, 4, 2, _Float16, true>
        <<<(T_LEN / 192) * (QKV_COLS / 256), 512, 0, stream>>>(hs16, qkvw16, qkv16, vtb);
    norm_rope_kernel<<<dim3(T_LEN, NH + NKV), 128, 0, stream>>>(qkv16, q_nw, k_nw, pos);
    // pipelined retention: 48 x 8 blocks, 2 q-heads per block
    attn_mfma2<<<dim3(T_LEN / AQT, NKV), 256, 0, stream>>>(qkv16, vtb, cgb, hs16);
    // output projection: 192x128 tiles, 16x16 = 256 blocks (2 blocks/CU)
    gemm_mph<T_LEN, HID_DIM, HID_DIM, 192, 128, 4, 2, 4, float, false>
        <<<(T_LEN / 192) * (HID_DIM / 128), 512, 0, stream>>>(hs16, ow16, (float*)d_out, nullptr);
    (void)in_sizes; (void)n_in; (void)out_size; (void)ws_size;
}

// Round 10
// 192.961 us; speedup vs baseline: 1.1320x; 1.0681x over previous
//
#include <hip/hip_runtime.h>
#include <math.h>

#define T_LEN 3072
#define HID_DIM 2048
#define NH 16
#define NKV 8
#define HD 128
#define QKV_COLS ((NH + 2 * NKV) * HD)   // 4096
#define V_OFF (NH * HD + NKV * HD)       // 3072
#define RMS_EPS 1e-6f
#define NORM_EPS 1e-6f
#define THETA 10000.0f
#define SCALE 0.08838834764831845f       // 128^-0.5

#define BAND 256   // exp(-0.65*256)=e^-167 -> exactly 0 in f32; validated round 1
#define AQT 64     // q rows per attn block

typedef __attribute__((ext_vector_type(8))) _Float16 f16x8;
typedef __attribute__((ext_vector_type(4))) float f32x4;

__device__ __forceinline__ void gload_lds16(const void* g, void* l) {
    __builtin_amdgcn_global_load_lds((const __attribute__((address_space(1))) void*)g,
                                     (__attribute__((address_space(3))) void*)l, 16, 0, 0);
}
__device__ __forceinline__ void gload_lds4(const void* g, void* l) {
    __builtin_amdgcn_global_load_lds((const __attribute__((address_space(1))) void*)g,
                                     (__attribute__((address_space(3))) void*)l, 4, 0, 0);
}

#define VMCNT_I(n) asm volatile("s_waitcnt vmcnt(" #n ")" ::: "memory")

// ---------------------------------------------------------------------------
// m201-granularity f16 MFMA GEMM (structure validated r9). Both GEMMs now use
// BM=192, BN=128 (HALF=20KB, LDS=80KB -> 2 blocks/CU; full-machine grids:
// qkv 16x32=512, oproj 16x16=256). Per K-half: 1 phase of {ds_read 3 af + 4 bf
// || stage half of t+1 -> barrier -> lgkmcnt(0) -> setprio + 12 MFMA ->
// [vmcnt(4) at half boundary] -> barrier}. Chunk swizzle c^((row>>1)&3)
// (0 conflicts r5-r9).
// ---------------------------------------------------------------------------
template <int M, int N, int K, int BM, int BN, int WM, int WN, int WPE,
          typename OutT, bool SPLIT_V>
__global__ __launch_bounds__(512, WPE) void gemm_mph(const _Float16* __restrict__ A,
                                                     const _Float16* __restrict__ Bp,
                                                     OutT* __restrict__ C,
                                                     _Float16* __restrict__ vt) {
    constexpr int MI = BM / WM / 16;
    constexpr int NGROUP = (MI >= 6) ? 2 : 1;
    constexpr int GSZ = MI / NGROUP;
    constexpr int NI = BN / WN / 16;
    constexpr int NT = K / 64;
    constexpr int NX = N / BN;
    constexpr int HALF = (BM + BN) * 64;
    constexpr int FULL = HALF / 8192;
    constexpr int REM = HALF - FULL * 8192;
    constexpr int NISS = FULL + (REM ? 2 : 0);
    static_assert(REM == 0 || REM == 4096, "staging remainder must be 4KB");
    __shared__ char lds[2 * 2 * HALF];

    const int tid = threadIdx.x, lane = tid & 63, wid = tid >> 6;
    const int wm = wid / WN, wn = wid % WN;
    const int q8 = gridDim.x >> 3;
    const int sw = (blockIdx.x & 7) * q8 + (blockIdx.x >> 3);
    const int brow = (sw / NX) * BM, bcol = (sw % NX) * BN;

    auto stage_half = [&](int t, int kh) {
        char* hb = lds + (size_t)((t & 1) * 2 + kh) * HALF;
        const int k0 = t * 64 + kh * 32;
#pragma unroll
        for (int j = 0; j < FULL; ++j) {
            const int L = j * 8192 + tid * 16;
            if (L < BM * 64) {
                const int r = L >> 6;
                const int c = ((L >> 4) & 3) ^ ((r >> 1) & 3);
                gload_lds16(A + (size_t)(brow + r) * K + k0 + c * 8, hb + L);
            } else {
                const int Lb = L - BM * 64;
                const int r = Lb >> 6;
                const int c = ((Lb >> 4) & 3) ^ ((r >> 1) & 3);
                gload_lds16(Bp + (size_t)(bcol + r) * K + k0 + c * 8, hb + L);
            }
        }
        if constexpr (REM != 0) {
#pragma unroll
            for (int j = 0; j < 2; ++j) {
                const int L = FULL * 8192 + j * 2048 + (tid >> 6) * 256 + (tid & 63) * 4;
                const int Lb = L - BM * 64;
                const int r = Lb >> 6;
                const int wb = Lb & 63;
                const int c = (wb >> 4) ^ ((r >> 1) & 3);
                gload_lds4(Bp + (size_t)(bcol + r) * K + k0 + c * 8 + ((wb & 15) >> 1),
                           hb + (L & ~255));
            }
        }
    };
    auto wait_n = [&]() {
        if constexpr (NISS == 5) VMCNT_I(5);
        else if constexpr (NISS == 4) VMCNT_I(4);
        else VMCNT_I(3);
    };

    f32x4 acc[MI][NI];
#pragma unroll
    for (int mi = 0; mi < MI; ++mi)
#pragma unroll
        for (int ni = 0; ni < NI; ++ni) acc[mi][ni] = (f32x4){0.f, 0.f, 0.f, 0.f};

    stage_half(0, 0);
    stage_half(0, 1);
    wait_n();
    asm volatile("" ::: "memory");
    __builtin_amdgcn_s_barrier();
    asm volatile("" ::: "memory");

    for (int t = 0; t < NT; ++t) {
        const char* buf = lds + (size_t)(t & 1) * 2 * HALF;
#pragma unroll
        for (int kh = 0; kh < 2; ++kh) {
            const char* ab = buf + kh * HALF;
            const char* bb = ab + BM * 64;
            f16x8 bf[NI];
#pragma unroll
            for (int g = 0; g < NGROUP; ++g) {
                if (g == 0) {
#pragma unroll
                    for (int ni = 0; ni < NI; ++ni) {
                        const int r = wn * (BN / WN) + ni * 16 + (lane & 15);
                        bf[ni] = *reinterpret_cast<const f16x8*>(
                            bb + r * 64 + ((((lane >> 4)) ^ ((r >> 1) & 3)) << 4));
                    }
                }
                f16x8 af[GSZ];
#pragma unroll
                for (int m = 0; m < GSZ; ++m) {
                    const int r = wm * (BM / WM) + (g * GSZ + m) * 16 + (lane & 15);
                    af[m] = *reinterpret_cast<const f16x8*>(
                        ab + r * 64 + ((((lane >> 4)) ^ ((r >> 1) & 3)) << 4));
                }
                if (g == 0 && t + 1 < NT) stage_half(t + 1, kh);
                asm volatile("" ::: "memory");
                __builtin_amdgcn_s_barrier();
                asm volatile("s_waitcnt lgkmcnt(0)" ::: "memory");
                __builtin_amdgcn_sched_barrier(0);
                __builtin_amdgcn_s_setprio(1);
#pragma unroll
                for (int m = 0; m < GSZ; ++m)
#pragma unroll
                    for (int ni = 0; ni < NI; ++ni)
                        acc[g * GSZ + m][ni] = __builtin_amdgcn_mfma_f32_16x16x32_f16(
                            af[m], bf[ni], acc[g * GSZ + m][ni], 0, 0, 0);
                __builtin_amdgcn_s_setprio(0);
                if (g == NGROUP - 1) {
                    if (kh == 0) {
                        if (t == NT - 1) VMCNT_I(0);
                        else wait_n();
                    } else if (t + 1 < NT) {
                        wait_n();
                    }
                }
                asm volatile("" ::: "memory");
                __builtin_amdgcn_s_barrier();
                asm volatile("" ::: "memory");
            }
        }
    }

    if (SPLIT_V && bcol >= V_OFF) {
#pragma unroll
        for (int mi = 0; mi < MI; ++mi)
#pragma unroll
            for (int ni = 0; ni < NI; ++ni) {
                const int col = bcol - V_OFF + wn * (BN / WN) + ni * 16 + (lane & 15);
                const int rb = brow + wm * (BM / WM) + mi * 16 + (lane >> 4) * 4;
#pragma unroll
                for (int j = 0; j < 4; ++j)
                    vt[(size_t)col * M + rb + j] = (_Float16)acc[mi][ni][j];
            }
    } else {
#pragma unroll
        for (int mi = 0; mi < MI; ++mi)
#pragma unroll
            for (int ni = 0; ni < NI; ++ni) {
                const int col = bcol + wn * (BN / WN) + ni * 16 + (lane & 15);
                const int rb = brow + wm * (BM / WM) + mi * 16 + (lane >> 4) * 4;
#pragma unroll
                for (int j = 0; j < 4; ++j)
                    C[(size_t)(rb + j) * N + col] = (OutT)acc[mi][ni][j];
            }
    }
}

// ---------------------------------------------------------------------------
__global__ __launch_bounds__(256) void cast_f32_f16(const float* __restrict__ in,
                                                    _Float16* __restrict__ out, int n) {
    const int i = (blockIdx.x * 256 + threadIdx.x) * 8;
    if (i >= n) return;
    float4 a = *reinterpret_cast<const float4*>(&in[i]);
    float4 b = *reinterpret_cast<const float4*>(&in[i + 4]);
    f16x8 o;
    o[0] = (_Float16)a.x; o[1] = (_Float16)a.y; o[2] = (_Float16)a.z; o[3] = (_Float16)a.w;
    o[4] = (_Float16)b.x; o[5] = (_Float16)b.y; o[6] = (_Float16)b.z; o[7] = (_Float16)b.w;
    *reinterpret_cast<f16x8*>(&out[i]) = o;
}

// ---------------------------------------------------------------------------
// Fused: hs cast, gate = log_sigmoid(hs . g_w), AND rope cos/sin table
// (threads 0..63 compute the 64 freqs for this t once; reused by 24 heads).
// ---------------------------------------------------------------------------
__global__ __launch_bounds__(256) void cast_gate(const float* __restrict__ hs,
                                                 const float* __restrict__ g_w,
                                                 const int* __restrict__ pos,
                                                 _Float16* __restrict__ hs16,
                                                 float* __restrict__ gate,
                                                 float2* __restrict__ rope_tab) {
    const int t = blockIdx.x;
    const int tid = threadIdx.x, lane = tid & 63, wave = tid >> 6;
    const int i = tid * 8;
    const float* row = hs + (size_t)t * HID_DIM;
    float4 a = *reinterpret_cast<const float4*>(&row[i]);
    float4 b = *reinterpret_cast<const float4*>(&row[i + 4]);
    f16x8 o;
    o[0] = (_Float16)a.x; o[1] = (_Float16)a.y; o[2] = (_Float16)a.z; o[3] = (_Float16)a.w;
    o[4] = (_Float16)b.x; o[5] = (_Float16)b.y; o[6] = (_Float16)b.z; o[7] = (_Float16)b.w;
    *reinterpret_cast<f16x8*>(&hs16[(size_t)t * HID_DIM + i]) = o;

    if (tid < 64) {   // rope table for this t
        float inv_freq = powf(THETA, -(float)tid * (1.0f / 64.0f));
        float ang = (float)pos[t] * inv_freq;
        float sn, cs;
        sincosf(ang, &sn, &cs);
        rope_tab[(size_t)t * 64 + tid] = make_float2(cs, sn);
    }

    float s[NKV];
#pragma unroll
    for (int h = 0; h < NKV; ++h) {
        const float4 wa = *reinterpret_cast<const float4*>(&g_w[(size_t)h * HID_DIM + i]);
        const float4 wb = *reinterpret_cast<const float4*>(&g_w[(size_t)h * HID_DIM + i + 4]);
        s[h] = a.x * wa.x + a.y * wa.y + a.z * wa.z + a.w * wa.w
             + b.x * wb.x + b.y * wb.y + b.z * wb.z + b.w * wb.w;
    }
#pragma unroll
    for (int off = 32; off > 0; off >>= 1)
#pragma unroll
        for (int h = 0; h < NKV; ++h) s[h] += __shfl_down(s[h], off, 64);
    __shared__ float red[4][NKV];
    if (lane == 0)
#pragma unroll
        for (int h = 0; h < NKV; ++h) red[wave][h] = s[h];
    __syncthreads();
    if (tid < NKV) {
        float x = red[0][tid] + red[1][tid] + red[2][tid] + red[3][tid];
        float ls = fminf(x, 0.f) - log1pf(expf(-fabsf(x)));
        gate[(size_t)t * NKV + tid] = ls;
    }
}

// ---------------------------------------------------------------------------
__global__ __launch_bounds__(1024) void cumsum_kernel(const float* __restrict__ gate,
                                                      float* __restrict__ cg) {
    const int h = blockIdx.x;
    const int tid = threadIdx.x;
    float v0 = gate[(size_t)(tid * 3 + 0) * NKV + h];
    float v1 = gate[(size_t)(tid * 3 + 1) * NKV + h];
    float v2 = gate[(size_t)(tid * 3 + 2) * NKV + h];
    float p0 = v0, p1 = v0 + v1, p2 = v0 + v1 + v2;
    __shared__ float s[1024];
    s[tid] = p2;
    __syncthreads();
    float sum = p2;
    for (int off = 1; off < 1024; off <<= 1) {
        float add = (tid >= off) ? s[tid - off] : 0.f;
        __syncthreads();
        sum += add;
        s[tid] = sum;
        __syncthreads();
    }
    float base = sum - p2;
    cg[(size_t)(tid * 3 + 0) * NKV + h] = base + p0;
    cg[(size_t)(tid * 3 + 1) * NKV + h] = base + p1;
    cg[(size_t)(tid * 3 + 2) * NKV + h] = base + p2;
}

// ---------------------------------------------------------------------------
// RMSNorm + RoPE, trig from precomputed table (cos,sin per (t, i)).
// ---------------------------------------------------------------------------
__global__ __launch_bounds__(128) void norm_rope_kernel(_Float16* __restrict__ qkv,
                                                        const float* __restrict__ qw,
                                                        const float* __restrict__ kw,
                                                        const float2* __restrict__ rope_tab) {
    const int t = blockIdx.x;
    const int head = blockIdx.y;  // 0..23
    const int d = threadIdx.x;
    const bool is_q = head < NH;
    _Float16* row = qkv + (size_t)t * QKV_COLS + (is_q ? head * HD : NH * HD + (head - NH) * HD);
    float x = (float)row[d];
    float ss = x * x;
#pragma unroll
    for (int off = 32; off > 0; off >>= 1) ss += __shfl_down(ss, off, 64);
    __shared__ float r2[2];
    __shared__ float vals[HD];
    if ((threadIdx.x & 63) == 0) r2[threadIdx.x >> 6] = ss;
    __syncthreads();
    float var = (r2[0] + r2[1]) * (1.0f / HD);
    float rs = rsqrtf(var + RMS_EPS);
    const float* w = is_q ? qw : kw;
    float v = x * rs * w[d];
    vals[d] = v;
    __syncthreads();
    float2 cs = rope_tab[(size_t)t * 64 + (d & 63)];
    float out;
    if (d < 64) out = v * cs.x - vals[d + 64] * cs.y;
    else        out = v * cs.x + vals[d - 64] * cs.y;
    if (is_q) out *= SCALE;
    row[d] = (_Float16)out;
}

// ---------------------------------------------------------------------------
// Pipelined MFMA banded retention (verified round 6, unchanged).
// ---------------------------------------------------------------------------
__global__ __launch_bounds__(256, 2) void attn_mfma2(const _Float16* __restrict__ qkv,
                                                     const _Float16* __restrict__ vt,
                                                     const float* __restrict__ cg,
                                                     _Float16* __restrict__ out) {
    const int h = blockIdx.y;             // kv head 0..7
    const int t0 = blockIdx.x * AQT;
    const int tid = threadIdx.x, lane = tid & 63, wid = tid >> 6;

    __shared__ char buf[4][16384];
    __shared__ char WsB[2][4096];
    __shared__ float cgS[BAND + AQT];

    const int s_lo = (t0 >= BAND) ? t0 - BAND : 0;
    const int NT = (t0 + AQT - s_lo) >> 5;
    const int span = t0 + AQT - s_lo;

    for (int i = tid; i < span; i += 256)
        cgS[i] = cg[(size_t)(s_lo + i) * NKV + h];

    f16x8 qa[2][4];
    {
        const int qrow = t0 + wid * 16 + (lane & 15);
#pragma unroll
        for (int hh = 0; hh < 2; ++hh) {
            const _Float16* qp = qkv + (size_t)qrow * QKV_COLS + (2 * h + hh) * HD + (lane >> 4) * 8;
#pragma unroll
            for (int kq = 0; kq < 4; ++kq)
                qa[hh][kq] = *reinterpret_cast<const f16x8*>(qp + kq * 32);
        }
    }

    auto stage = [&](int t) {
        const int s0 = s_lo + t * 32;
        char* kd = (char*)buf + (size_t)(t & 3) * 16384;
        char* vd = kd + 8192;
#pragma unroll
        for (int i = 0; i < 2; ++i) {
            const int r = i * 16 + (tid >> 4);
            const int celem = (((tid & 15) * 16) ^ ((r & 7) << 4)) >> 1;
            gload_lds16(qkv + (size_t)(s0 + r) * QKV_COLS + NH * HD + h * HD + celem,
                        kd + i * 4096 + tid * 16);
        }
#pragma unroll
        for (int i = 0; i < 2; ++i) {
            const int d = i * 64 + (tid >> 2);
            const int key = (d ^ (d >> 2)) & 3;
            gload_lds16(vt + (size_t)(h * HD + d) * T_LEN + s0 + 8 * ((tid & 3) ^ key),
                        vd + i * 4096 + tid * 16);
        }
    };

    stage(0); stage(1); stage(2);
    __syncthreads();

    float cqr[4];
#pragma unroll
    for (int j = 0; j < 4; ++j)
        cqr[j] = cgS[(span - AQT) + wid * 16 + (lane >> 4) * 4 + j];

    f32x4 acc_o[2][8];
#pragma unroll
    for (int hh = 0; hh < 2; ++hh)
#pragma unroll
        for (int nq = 0; nq < 8; ++nq) acc_o[hh][nq] = (f32x4){0.f, 0.f, 0.f, 0.f};
    float dsum[2][4] = {{0.f, 0.f, 0.f, 0.f}, {0.f, 0.f, 0.f, 0.f}};

    for (int t = 0; t < NT; ++t) {
        if (t + 3 < NT) stage(t + 3);
        const char* kbase = (const char*)buf + (size_t)(t & 3) * 16384;
        const char* vbase = kbase + 8192;
        const int s0 = s_lo + t * 32;

        f16x8 kf[2][4];
#pragma unroll
        for (int c = 0; c < 2; ++c) {
            const int rr = c * 16 + (lane & 15);
#pragma unroll
            for (int kq = 0; kq < 4; ++kq) {
                const int bi = (kq * 64 + (lane >> 4) * 16) ^ ((rr & 7) << 4);
                kf[c][kq] = *reinterpret_cast<const f16x8*>(kbase + rr * 256 + bi);
            }
        }
        float csv[2];
        csv[0] = cgS[t * 32 + (lane & 15)];
        csv[1] = cgS[t * 32 + 16 + (lane & 15)];

#pragma unroll
        for (int hh = 0; hh < 2; ++hh) {
            f32x4 accs[2];
            accs[0] = (f32x4){0.f, 0.f, 0.f, 0.f};
            accs[1] = (f32x4){0.f, 0.f, 0.f, 0.f};
#pragma unroll
            for (int c = 0; c < 2; ++c)
#pragma unroll
                for (int kq = 0; kq < 4; ++kq)
                    accs[c] = __builtin_amdgcn_mfma_f32_16x16x32_f16(
                        qa[hh][kq], kf[c][kq], accs[c], 0, 0, 0);
#pragma unroll
            for (int c = 0; c < 2; ++c) {
                const int sg = s0 + c * 16 + (lane & 15);
#pragma unroll
                for (int j = 0; j < 4; ++j) {
                    const int qg = t0 + wid * 16 + (lane >> 4) * 4 + j;
                    const float sv = accs[c][j];
                    const float w = (sg <= qg) ? __expf(cqr[j] - csv[c]) * sv * sv : 0.f;
                    const _Float16 wh = (_Float16)w;
                    dsum[hh][j] += (float)wh;
                    const int q = wid * 16 + (lane >> 4) * 4 + j;
                    const int addr = q * 64 +
                        ((2 * (c * 16 + (lane & 15))) ^ (((q ^ (q >> 2)) & 3) << 4));
                    *(_Float16*)(WsB[hh] + addr) = wh;
                }
            }
        }
        asm volatile("s_waitcnt lgkmcnt(0)" ::: "memory");
        __builtin_amdgcn_sched_barrier(0);

        const int qr = wid * 16 + (lane & 15);
        const int wb = qr * 64 + (((lane >> 4) * 16) ^ (((qr ^ (qr >> 2)) & 3) << 4));
        f16x8 wf0 = *reinterpret_cast<const f16x8*>(WsB[0] + wb);
        f16x8 wf1 = *reinterpret_cast<const f16x8*>(WsB[1] + wb);
        f16x8 vf[8];
#pragma unroll
        for (int nq = 0; nq < 8; ++nq) {
            const int dr = nq * 16 + (lane & 15);
            const int vb = dr * 64 + (((lane >> 4) * 16) ^ (((dr ^ (dr >> 2)) & 3) << 4));
            vf[nq] = *reinterpret_cast<const f16x8*>(vbase + vb);
        }
        __builtin_amdgcn_s_setprio(1);
#pragma unroll
        for (int nq = 0; nq < 8; ++nq) {
            acc_o[0][nq] = __builtin_amdgcn_mfma_f32_16x16x32_f16(wf0, vf[nq], acc_o[0][nq], 0, 0, 0);
            acc_o[1][nq] = __builtin_amdgcn_mfma_f32_16x16x32_f16(wf1, vf[nq], acc_o[1][nq], 0, 0, 0);
        }
        __builtin_amdgcn_s_setprio(0);

        const int rem = NT - 1 - t;
        if (rem >= 3)      asm volatile("s_waitcnt vmcnt(8)" ::: "memory");
        else if (rem == 2) asm volatile("s_waitcnt vmcnt(4)" ::: "memory");
        else if (rem == 1) asm volatile("s_waitcnt vmcnt(0)" ::: "memory");
        asm volatile("" ::: "memory");
        if (rem > 0) __builtin_amdgcn_s_barrier();
        asm volatile("" ::: "memory");
    }

#pragma unroll
    for (int hh = 0; hh < 2; ++hh) {
        float inv[4];
#pragma unroll
        for (int j = 0; j < 4; ++j) {
            float d = dsum[hh][j];
            d += __shfl_xor(d, 1, 64);
            d += __shfl_xor(d, 2, 64);
            d += __shfl_xor(d, 4, 64);
            d += __shfl_xor(d, 8, 64);
            inv[j] = 1.f / (d + NORM_EPS);
        }
#pragma unroll
        for (int nq = 0; nq < 8; ++nq)
#pragma unroll
            for (int j = 0; j < 4; ++j) {
                const int row = t0 + wid * 16 + (lane >> 4) * 4 + j;
                out[(size_t)row * (NH * HD) + (2 * h + hh) * HD + nq * 16 + (lane & 15)] =
                    (_Float16)(acc_o[hh][nq][j] * inv[j]);
            }
    }
}

// ---------------------------------------------------------------------------
extern "C" void kernel_launch(void* const* d_in, const int* in_sizes, int n_in,
                              void* d_out, int out_size, void* d_ws, size_t ws_size,
                              hipStream_t stream) {
    const float* hs    = (const float*)d_in[0];
    const float* qkv_w = (const float*)d_in[1];
    const float* g_w   = (const float*)d_in[2];
    const float* o_w   = (const float*)d_in[3];
    const float* q_nw  = (const float*)d_in[4];
    const float* k_nw  = (const float*)d_in[5];
    const int*   pos   = (const int*)d_in[6];

    _Float16* hs16   = (_Float16*)d_ws;                      // 3072*2048 (reused for attn out)
    _Float16* qkvw16 = hs16 + (size_t)T_LEN * HID_DIM;       // 4096*2048
    _Float16* ow16   = qkvw16 + (size_t)QKV_COLS * HID_DIM;  // 2048*2048
    _Float16* qkv16  = ow16 + (size_t)HID_DIM * HID_DIM;     // 3072*4096 (v region unused)
    _Float16* vtb    = qkv16 + (size_t)T_LEN * QKV_COLS;     // 1024*3072 (V transposed)
    float* gate = (float*)(vtb + (size_t)NKV * HD * T_LEN);
    float* cgb  = gate + (size_t)T_LEN * NKV;
    float2* rope_tab = (float2*)(cgb + (size_t)T_LEN * NKV); // 3072*64*8B

    cast_gate<<<T_LEN, 256, 0, stream>>>(hs, g_w, pos, hs16, gate, rope_tab);
    cast_f32_f16<<<(QKV_COLS * HID_DIM) / 2048, 256, 0, stream>>>(qkv_w, qkvw16, QKV_COLS * HID_DIM);
    cast_f32_f16<<<(HID_DIM * HID_DIM) / 2048, 256, 0, stream>>>(o_w, ow16, HID_DIM * HID_DIM);
    cumsum_kernel<<<NKV, 1024, 0, stream>>>(gate, cgb);
    // qkv projection: 192x128 tiles, 16x32 = 512 blocks (2 blocks/CU)
    gemm_mph<T_LEN, QKV_COLS, HID_DIM, 192, 128, 4, 2, 4, _Float16, true>
        <<<(T_LEN / 192) * (QKV_COLS / 128), 512, 0, stream>>>(hs16, qkvw16, qkv16, vtb);
    norm_rope_kernel<<<dim3(T_LEN, NH + NKV), 128, 0, stream>>>(qkv16, q_nw, k_nw, rope_tab);
    // pipelined retention: 48 x 8 blocks, 2 q-heads per block
    attn_mfma2<<<dim3(T_LEN / AQT, NKV), 256, 0, stream>>>(qkv16, vtb, cgb, hs16);
    // output projection: 192x128 tiles, 16x16 = 256 blocks (2 blocks/CU)
    gemm_mph<T_LEN, HID_DIM, HID_DIM, 192, 128, 4, 2, 4, float, false>
        <<<(T_LEN / 192) * (HID_DIM / 128), 512, 0, stream>>>(hs16, ow16, (float*)d_out, nullptr);
    (void)in_sizes; (void)n_in; (void)out_size; (void)ws_size;
}

// Round 11
// 182.472 us; speedup vs baseline: 1.1971x; 1.0575x over previous
//
#include <hip/hip_runtime.h>
#include <math.h>

#define T_LEN 3072
#define HID_DIM 2048
#define NH 16
#define NKV 8
#define HD 128
#define QKV_COLS ((NH + 2 * NKV) * HD)   // 4096
#define V_OFF (NH * HD + NKV * HD)       // 3072
#define RMS_EPS 1e-6f
#define NORM_EPS 1e-6f
#define THETA 10000.0f
#define SCALE 0.08838834764831845f       // 128^-0.5

#define BAND 256   // exp(-0.65*256)=e^-167 -> exactly 0 in f32; validated round 1
#define AQT 64     // q rows per attn block

typedef __attribute__((ext_vector_type(8))) _Float16 f16x8;
typedef __attribute__((ext_vector_type(4))) float f32x4;

__device__ __forceinline__ void gload_lds16(const void* g, void* l) {
    __builtin_amdgcn_global_load_lds((const __attribute__((address_space(1))) void*)g,
                                     (__attribute__((address_space(3))) void*)l, 16, 0, 0);
}
__device__ __forceinline__ void gload_lds4(const void* g, void* l) {
    __builtin_amdgcn_global_load_lds((const __attribute__((address_space(1))) void*)g,
                                     (__attribute__((address_space(3))) void*)l, 4, 0, 0);
}

#define VMCNT_I(n) asm volatile("s_waitcnt vmcnt(" #n ")" ::: "memory")

// ---------------------------------------------------------------------------
// m201-granularity f16 MFMA GEMM (schedule validated r9/r10; 0 conflicts).
// qkv: BM=192 BN=256 (r9 config, 63.5us measured). FUSE_NR: RMSNorm+RoPE
// fused into the epilogue for q/k tiles (tile never straddles q/k/v; holds
// 2 complete heads). Wave pair (wn^1) = the two 64-d halves of one head:
// SS via shfl_xor -> LDS parity combine -> normalize f32 acc -> LDS exchange
// (stride 136B) -> rope from table -> store. V tiles: transposed vt write.
// ---------------------------------------------------------------------------
template <int M, int N, int K, int BM, int BN, int WM, int WN, int WPE,
          typename OutT, bool SPLIT_V, bool FUSE_NR>
__global__ __launch_bounds__(512, WPE) void gemm_mph(const _Float16* __restrict__ A,
                                                     const _Float16* __restrict__ Bp,
                                                     OutT* __restrict__ C,
                                                     _Float16* __restrict__ vt,
                                                     const float* __restrict__ qw,
                                                     const float* __restrict__ kw,
                                                     const float2* __restrict__ rope_tab) {
    constexpr int MI = BM / WM / 16;
    constexpr int NGROUP = (MI >= 6) ? 2 : 1;
    constexpr int GSZ = MI / NGROUP;
    constexpr int NI = BN / WN / 16;
    constexpr int NT = K / 64;
    constexpr int NX = N / BN;
    constexpr int HALF = (BM + BN) * 64;
    constexpr int FULL = HALF / 8192;
    constexpr int REM = HALF - FULL * 8192;
    constexpr int NISS = FULL + (REM ? 2 : 0);
    static_assert(REM == 0 || REM == 4096, "staging remainder must be 4KB");
    __shared__ char lds[2 * 2 * HALF];

    const int tid = threadIdx.x, lane = tid & 63, wid = tid >> 6;
    const int wm = wid / WN, wn = wid % WN;
    const int q8 = gridDim.x >> 3;
    const int sw = (blockIdx.x & 7) * q8 + (blockIdx.x >> 3);
    const int brow = (sw / NX) * BM, bcol = (sw % NX) * BN;

    auto stage_half = [&](int t, int kh) {
        char* hb = lds + (size_t)((t & 1) * 2 + kh) * HALF;
        const int k0 = t * 64 + kh * 32;
#pragma unroll
        for (int j = 0; j < FULL; ++j) {
            const int L = j * 8192 + tid * 16;
            if (L < BM * 64) {
                const int r = L >> 6;
                const int c = ((L >> 4) & 3) ^ ((r >> 1) & 3);
                gload_lds16(A + (size_t)(brow + r) * K + k0 + c * 8, hb + L);
            } else {
                const int Lb = L - BM * 64;
                const int r = Lb >> 6;
                const int c = ((Lb >> 4) & 3) ^ ((r >> 1) & 3);
                gload_lds16(Bp + (size_t)(bcol + r) * K + k0 + c * 8, hb + L);
            }
        }
        if constexpr (REM != 0) {
#pragma unroll
            for (int j = 0; j < 2; ++j) {
                const int L = FULL * 8192 + j * 2048 + (tid >> 6) * 256 + (tid & 63) * 4;
                const int Lb = L - BM * 64;
                const int r = Lb >> 6;
                const int wb = Lb & 63;
                const int c = (wb >> 4) ^ ((r >> 1) & 3);
                gload_lds4(Bp + (size_t)(bcol + r) * K + k0 + c * 8 + ((wb & 15) >> 1),
                           hb + (L & ~255));
            }
        }
    };
    auto wait_n = [&]() {
        if constexpr (NISS == 5) VMCNT_I(5);
        else if constexpr (NISS == 4) VMCNT_I(4);
        else VMCNT_I(3);
    };

    f32x4 acc[MI][NI];
#pragma unroll
    for (int mi = 0; mi < MI; ++mi)
#pragma unroll
        for (int ni = 0; ni < NI; ++ni) acc[mi][ni] = (f32x4){0.f, 0.f, 0.f, 0.f};

    stage_half(0, 0);
    stage_half(0, 1);
    wait_n();
    asm volatile("" ::: "memory");
    __builtin_amdgcn_s_barrier();
    asm volatile("" ::: "memory");

    for (int t = 0; t < NT; ++t) {
        const char* buf = lds + (size_t)(t & 1) * 2 * HALF;
#pragma unroll
        for (int kh = 0; kh < 2; ++kh) {
            const char* ab = buf + kh * HALF;
            const char* bb = ab + BM * 64;
            f16x8 bf[NI];
#pragma unroll
            for (int g = 0; g < NGROUP; ++g) {
                if (g == 0) {
#pragma unroll
                    for (int ni = 0; ni < NI; ++ni) {
                        const int r = wn * (BN / WN) + ni * 16 + (lane & 15);
                        bf[ni] = *reinterpret_cast<const f16x8*>(
                            bb + r * 64 + ((((lane >> 4)) ^ ((r >> 1) & 3)) << 4));
                    }
                }
                f16x8 af[GSZ];
#pragma unroll
                for (int m = 0; m < GSZ; ++m) {
                    const int r = wm * (BM / WM) + (g * GSZ + m) * 16 + (lane & 15);
                    af[m] = *reinterpret_cast<const f16x8*>(
                        ab + r * 64 + ((((lane >> 4)) ^ ((r >> 1) & 3)) << 4));
                }
                if (g == 0 && t + 1 < NT) stage_half(t + 1, kh);
                asm volatile("" ::: "memory");
                __builtin_amdgcn_s_barrier();
                asm volatile("s_waitcnt lgkmcnt(0)" ::: "memory");
                __builtin_amdgcn_sched_barrier(0);
                __builtin_amdgcn_s_setprio(1);
#pragma unroll
                for (int m = 0; m < GSZ; ++m)
#pragma unroll
                    for (int ni = 0; ni < NI; ++ni)
                        acc[g * GSZ + m][ni] = __builtin_amdgcn_mfma_f32_16x16x32_f16(
                            af[m], bf[ni], acc[g * GSZ + m][ni], 0, 0, 0);
                __builtin_amdgcn_s_setprio(0);
                if (g == NGROUP - 1) {
                    if (kh == 0) {
                        if (t == NT - 1) VMCNT_I(0);
                        else wait_n();
                    } else if (t + 1 < NT) {
                        wait_n();
                    }
                }
                asm volatile("" ::: "memory");
                __builtin_amdgcn_s_barrier();
                asm volatile("" ::: "memory");
            }
        }
    }

    if constexpr (FUSE_NR) {
        if (bcol >= V_OFF) {   // V tile -> transposed write
#pragma unroll
            for (int mi = 0; mi < MI; ++mi)
#pragma unroll
                for (int ni = 0; ni < NI; ++ni) {
                    const int col = bcol - V_OFF + wn * (BN / WN) + ni * 16 + (lane & 15);
                    const int rb = brow + wm * (BM / WM) + mi * 16 + (lane >> 4) * 4;
#pragma unroll
                    for (int j = 0; j < 4; ++j)
                        vt[(size_t)col * M + rb + j] = (_Float16)acc[mi][ni][j];
                }
        } else {               // q/k tile -> fused RMSNorm + RoPE
            const bool is_q = (bcol < NH * HD);
            const float* nw = is_q ? qw : kw;
            const int hl = wn >> 1;       // head within tile
            const int dpart = wn & 1;     // 0: d<64, 1: d>=64
            float* ssbuf = (float*)lds;                    // [2 wm][2 hl][2 par][96]
            char* xch = (char*)lds + 4096;                 // 8 waves x 13056B
            char* myx = xch + wid * 13056;
            char* px  = xch + (wid ^ 1) * 13056;
            // 1) per-row SS over this wave's 64 cols
            float ssp[MI][4];
#pragma unroll
            for (int mi = 0; mi < MI; ++mi)
#pragma unroll
                for (int j = 0; j < 4; ++j) {
                    float s = 0.f;
#pragma unroll
                    for (int ni = 0; ni < NI; ++ni) {
                        float v = acc[mi][ni][j];
                        s += v * v;
                    }
                    s += __shfl_xor(s, 1, 64);
                    s += __shfl_xor(s, 2, 64);
                    s += __shfl_xor(s, 4, 64);
                    s += __shfl_xor(s, 8, 64);
                    ssp[mi][j] = s;
                }
            if ((lane & 15) == 0) {
#pragma unroll
                for (int mi = 0; mi < MI; ++mi)
#pragma unroll
                    for (int j = 0; j < 4; ++j) {
                        const int rl = mi * 16 + (lane >> 4) * 4 + j;
                        ssbuf[((wm * 2 + hl) * 2 + dpart) * 96 + rl] = ssp[mi][j];
                    }
            }
            __syncthreads();
            // 2) combine parities, normalize, write exchange
            float rsv[MI][4];
#pragma unroll
            for (int mi = 0; mi < MI; ++mi)
#pragma unroll
                for (int j = 0; j < 4; ++j) {
                    const int rl = mi * 16 + (lane >> 4) * 4 + j;
                    float ss2 = ssbuf[((wm * 2 + hl) * 2 + 0) * 96 + rl]
                              + ssbuf[((wm * 2 + hl) * 2 + 1) * 96 + rl];
                    rsv[mi][j] = rsqrtf(ss2 * (1.0f / HD) + RMS_EPS);
                }
#pragma unroll
            for (int mi = 0; mi < MI; ++mi)
#pragma unroll
                for (int ni = 0; ni < NI; ++ni) {
                    const int d = dpart * 64 + ni * 16 + (lane & 15);
                    const float w = nw[d];
#pragma unroll
                    for (int j = 0; j < 4; ++j) {
                        float v = acc[mi][ni][j] * rsv[mi][j] * w;
                        acc[mi][ni][j] = v;
                        const int rl = mi * 16 + (lane >> 4) * 4 + j;
                        *(_Float16*)(myx + rl * 136 + (ni * 16 + (lane & 15)) * 2) =
                            (_Float16)v;
                    }
                }
            __syncthreads();
            // 3) rope with partner half, store
#pragma unroll
            for (int mi = 0; mi < MI; ++mi)
#pragma unroll
                for (int j = 0; j < 4; ++j) {
                    const int rl = mi * 16 + (lane >> 4) * 4 + j;
                    const int trow = brow + wm * 96 + rl;
#pragma unroll
                    for (int ni = 0; ni < NI; ++ni) {
                        const int f = ni * 16 + (lane & 15);   // freq index
                        float2 cssn = rope_tab[(size_t)trow * 64 + f];
                        float p = (float)*(const _Float16*)(px + rl * 136 + f * 2);
                        float v = acc[mi][ni][j];
                        float outv = (dpart == 0) ? (v * cssn.x - p * cssn.y)
                                                  : (v * cssn.x + p * cssn.y);
                        if (is_q) outv *= SCALE;
                        const int col = bcol + wn * 64 + f;
                        C[(size_t)trow * N + col] = (OutT)outv;
                    }
                }
        }
    } else if (SPLIT_V && bcol >= V_OFF) {
#pragma unroll
        for (int mi = 0; mi < MI; ++mi)
#pragma unroll
            for (int ni = 0; ni < NI; ++ni) {
                const int col = bcol - V_OFF + wn * (BN / WN) + ni * 16 + (lane & 15);
                const int rb = brow + wm * (BM / WM) + mi * 16 + (lane >> 4) * 4;
#pragma unroll
                for (int j = 0; j < 4; ++j)
                    vt[(size_t)col * M + rb + j] = (_Float16)acc[mi][ni][j];
            }
    } else {
#pragma unroll
        for (int mi = 0; mi < MI; ++mi)
#pragma unroll
            for (int ni = 0; ni < NI; ++ni) {
                const int col = bcol + wn * (BN / WN) + ni * 16 + (lane & 15);
                const int rb = brow + wm * (BM / WM) + mi * 16 + (lane >> 4) * 4;
#pragma unroll
                for (int j = 0; j < 4; ++j)
                    C[(size_t)(rb + j) * N + col] = (OutT)acc[mi][ni][j];
            }
    }
}

// ---------------------------------------------------------------------------
// Merged weight cast: [0, na) from a, [na, na+nb) from b. na % 8 == 0.
// ---------------------------------------------------------------------------
__global__ __launch_bounds__(256) void cast_two(const float* __restrict__ a,
                                                const float* __restrict__ b,
                                                _Float16* __restrict__ oa,
                                                _Float16* __restrict__ ob,
                                                int na, int ntot) {
    const int i = (blockIdx.x * 256 + threadIdx.x) * 8;
    if (i >= ntot) return;
    const float* src = (i < na) ? a + i : b + (i - na);
    _Float16* dst = (i < na) ? oa + i : ob + (i - na);
    float4 x = *reinterpret_cast<const float4*>(src);
    float4 y = *reinterpret_cast<const float4*>(src + 4);
    f16x8 o;
    o[0] = (_Float16)x.x; o[1] = (_Float16)x.y; o[2] = (_Float16)x.z; o[3] = (_Float16)x.w;
    o[4] = (_Float16)y.x; o[5] = (_Float16)y.y; o[6] = (_Float16)y.z; o[7] = (_Float16)y.w;
    *reinterpret_cast<f16x8*>(dst) = o;
}

// ---------------------------------------------------------------------------
// Fused: hs cast, gate = log_sigmoid(hs . g_w), rope cos/sin table.
// ---------------------------------------------------------------------------
__global__ __launch_bounds__(256) void cast_gate(const float* __restrict__ hs,
                                                 const float* __restrict__ g_w,
                                                 const int* __restrict__ pos,
                                                 _Float16* __restrict__ hs16,
                                                 float* __restrict__ gate,
                                                 float2* __restrict__ rope_tab) {
    const int t = blockIdx.x;
    const int tid = threadIdx.x, lane = tid & 63, wave = tid >> 6;
    const int i = tid * 8;
    const float* row = hs + (size_t)t * HID_DIM;
    float4 a = *reinterpret_cast<const float4*>(&row[i]);
    float4 b = *reinterpret_cast<const float4*>(&row[i + 4]);
    f16x8 o;
    o[0] = (_Float16)a.x; o[1] = (_Float16)a.y; o[2] = (_Float16)a.z; o[3] = (_Float16)a.w;
    o[4] = (_Float16)b.x; o[5] = (_Float16)b.y; o[6] = (_Float16)b.z; o[7] = (_Float16)b.w;
    *reinterpret_cast<f16x8*>(&hs16[(size_t)t * HID_DIM + i]) = o;

    if (tid < 64) {
        float inv_freq = powf(THETA, -(float)tid * (1.0f / 64.0f));
        float ang = (float)pos[t] * inv_freq;
        float sn, cs;
        sincosf(ang, &sn, &cs);
        rope_tab[(size_t)t * 64 + tid] = make_float2(cs, sn);
    }

    float s[NKV];
#pragma unroll
    for (int h = 0; h < NKV; ++h) {
        const float4 wa = *reinterpret_cast<const float4*>(&g_w[(size_t)h * HID_DIM + i]);
        const float4 wb = *reinterpret_cast<const float4*>(&g_w[(size_t)h * HID_DIM + i + 4]);
        s[h] = a.x * wa.x + a.y * wa.y + a.z * wa.z + a.w * wa.w
             + b.x * wb.x + b.y * wb.y + b.z * wb.z + b.w * wb.w;
    }
#pragma unroll
    for (int off = 32; off > 0; off >>= 1)
#pragma unroll
        for (int h = 0; h < NKV; ++h) s[h] += __shfl_down(s[h], off, 64);
    __shared__ float red[4][NKV];
    if (lane == 0)
#pragma unroll
        for (int h = 0; h < NKV; ++h) red[wave][h] = s[h];
    __syncthreads();
    if (tid < NKV) {
        float x = red[0][tid] + red[1][tid] + red[2][tid] + red[3][tid];
        float ls = fminf(x, 0.f) - log1pf(expf(-fabsf(x)));
        gate[(size_t)t * NKV + tid] = ls;
    }
}

// ---------------------------------------------------------------------------
__global__ __launch_bounds__(1024) void cumsum_kernel(const float* __restrict__ gate,
                                                      float* __restrict__ cg) {
    const int h = blockIdx.x;
    const int tid = threadIdx.x;
    float v0 = gate[(size_t)(tid * 3 + 0) * NKV + h];
    float v1 = gate[(size_t)(tid * 3 + 1) * NKV + h];
    float v2 = gate[(size_t)(tid * 3 + 2) * NKV + h];
    float p0 = v0, p1 = v0 + v1, p2 = v0 + v1 + v2;
    __shared__ float s[1024];
    s[tid] = p2;
    __syncthreads();
    float sum = p2;
    for (int off = 1; off < 1024; off <<= 1) {
        float add = (tid >= off) ? s[tid - off] : 0.f;
        __syncthreads();
        sum += add;
        s[tid] = sum;
        __syncthreads();
    }
    float base = sum - p2;
    cg[(size_t)(tid * 3 + 0) * NKV + h] = base + p0;
    cg[(size_t)(tid * 3 + 1) * NKV + h] = base + p1;
    cg[(size_t)(tid * 3 + 2) * NKV + h] = base + p2;
}

// ---------------------------------------------------------------------------
// Pipelined MFMA banded retention (verified round 6, unchanged).
// ---------------------------------------------------------------------------
__global__ __launch_bounds__(256, 2) void attn_mfma2(const _Float16* __restrict__ qkv,
                                                     const _Float16* __restrict__ vt,
                                                     const float* __restrict__ cg,
                                                     _Float16* __restrict__ out) {
    const int h = blockIdx.y;
    const int t0 = blockIdx.x * AQT;
    const int tid = threadIdx.x, lane = tid & 63, wid = tid >> 6;

    __shared__ char buf[4][16384];
    __shared__ char WsB[2][4096];
    __shared__ float cgS[BAND + AQT];

    const int s_lo = (t0 >= BAND) ? t0 - BAND : 0;
    const int NT = (t0 + AQT - s_lo) >> 5;
    const int span = t0 + AQT - s_lo;

    for (int i = tid; i < span; i += 256)
        cgS[i] = cg[(size_t)(s_lo + i) * NKV + h];

    f16x8 qa[2][4];
    {
        const int qrow = t0 + wid * 16 + (lane & 15);
#pragma unroll
        for (int hh = 0; hh < 2; ++hh) {
            const _Float16* qp = qkv + (size_t)qrow * QKV_COLS + (2 * h + hh) * HD + (lane >> 4) * 8;
#pragma unroll
            for (int kq = 0; kq < 4; ++kq)
                qa[hh][kq] = *reinterpret_cast<const f16x8*>(qp + kq * 32);
        }
    }

    auto stage = [&](int t) {
        const int s0 = s_lo + t * 32;
        char* kd = (char*)buf + (size_t)(t & 3) * 16384;
        char* vd = kd + 8192;
#pragma unroll
        for (int i = 0; i < 2; ++i) {
            const int r = i * 16 + (tid >> 4);
            const int celem = (((tid & 15) * 16) ^ ((r & 7) << 4)) >> 1;
            gload_lds16(qkv + (size_t)(s0 + r) * QKV_COLS + NH * HD + h * HD + celem,
                        kd + i * 4096 + tid * 16);
        }
#pragma unroll
        for (int i = 0; i < 2; ++i) {
            const int d = i * 64 + (tid >> 2);
            const int key = (d ^ (d >> 2)) & 3;
            gload_lds16(vt + (size_t)(h * HD + d) * T_LEN + s0 + 8 * ((tid & 3) ^ key),
                        vd + i * 4096 + tid * 16);
        }
    };

    stage(0); stage(1); stage(2);
    __syncthreads();

    float cqr[4];
#pragma unroll
    for (int j = 0; j < 4; ++j)
        cqr[j] = cgS[(span - AQT) + wid * 16 + (lane >> 4) * 4 + j];

    f32x4 acc_o[2][8];
#pragma unroll
    for (int hh = 0; hh < 2; ++hh)
#pragma unroll
        for (int nq = 0; nq < 8; ++nq) acc_o[hh][nq] = (f32x4){0.f, 0.f, 0.f, 0.f};
    float dsum[2][4] = {{0.f, 0.f, 0.f, 0.f}, {0.f, 0.f, 0.f, 0.f}};

    for (int t = 0; t < NT; ++t) {
        if (t + 3 < NT) stage(t + 3);
        const char* kbase = (const char*)buf + (size_t)(t & 3) * 16384;
        const char* vbase = kbase + 8192;
        const int s0 = s_lo + t * 32;

        f16x8 kf[2][4];
#pragma unroll
        for (int c = 0; c < 2; ++c) {
            const int rr = c * 16 + (lane & 15);
#pragma unroll
            for (int kq = 0; kq < 4; ++kq) {
                const int bi = (kq * 64 + (lane >> 4) * 16) ^ ((rr & 7) << 4);
                kf[c][kq] = *reinterpret_cast<const f16x8*>(kbase + rr * 256 + bi);
            }
        }
        float csv[2];
        csv[0] = cgS[t * 32 + (lane & 15)];
        csv[1] = cgS[t * 32 + 16 + (lane & 15)];

#pragma unroll
        for (int hh = 0; hh < 2; ++hh) {
            f32x4 accs[2];
            accs[0] = (f32x4){0.f, 0.f, 0.f, 0.f};
            accs[1] = (f32x4){0.f, 0.f, 0.f, 0.f};
#pragma unroll
            for (int c = 0; c < 2; ++c)
#pragma unroll
                for (int kq = 0; kq < 4; ++kq)
                    accs[c] = __builtin_amdgcn_mfma_f32_16x16x32_f16(
                        qa[hh][kq], kf[c][kq], accs[c], 0, 0, 0);
#pragma unroll
            for (int c = 0; c < 2; ++c) {
                const int sg = s0 + c * 16 + (lane & 15);
#pragma unroll
                for (int j = 0; j < 4; ++j) {
                    const int qg = t0 + wid * 16 + (lane >> 4) * 4 + j;
                    const float sv = accs[c][j];
                    const float w = (sg <= qg) ? __expf(cqr[j] - csv[c]) * sv * sv : 0.f;
                    const _Float16 wh = (_Float16)w;
                    dsum[hh][j] += (float)wh;
                    const int q = wid * 16 + (lane >> 4) * 4 + j;
                    const int addr = q * 64 +
                        ((2 * (c * 16 + (lane & 15))) ^ (((q ^ (q >> 2)) & 3) << 4));
                    *(_Float16*)(WsB[hh] + addr) = wh;
                }
            }
        }
        asm volatile("s_waitcnt lgkmcnt(0)" ::: "memory");
        __builtin_amdgcn_sched_barrier(0);

        const int qr = wid * 16 + (lane & 15);
        const int wb = qr * 64 + (((lane >> 4) * 16) ^ (((qr ^ (qr >> 2)) & 3) << 4));
        f16x8 wf0 = *reinterpret_cast<const f16x8*>(WsB[0] + wb);
        f16x8 wf1 = *reinterpret_cast<const f16x8*>(WsB[1] + wb);
        f16x8 vf[8];
#pragma unroll
        for (int nq = 0; nq < 8; ++nq) {
            const int dr = nq * 16 + (lane & 15);
            const int vb = dr * 64 + (((lane >> 4) * 16) ^ (((dr ^ (dr >> 2)) & 3) << 4));
            vf[nq] = *reinterpret_cast<const f16x8*>(vbase + vb);
        }
        __builtin_amdgcn_s_setprio(1);
#pragma unroll
        for (int nq = 0; nq < 8; ++nq) {
            acc_o[0][nq] = __builtin_amdgcn_mfma_f32_16x16x32_f16(wf0, vf[nq], acc_o[0][nq], 0, 0, 0);
            acc_o[1][nq] = __builtin_amdgcn_mfma_f32_16x16x32_f16(wf1, vf[nq], acc_o[1][nq], 0, 0, 0);
        }
        __builtin_amdgcn_s_setprio(0);

        const int rem = NT - 1 - t;
        if (rem >= 3)      asm volatile("s_waitcnt vmcnt(8)" ::: "memory");
        else if (rem == 2) asm volatile("s_waitcnt vmcnt(4)" ::: "memory");
        else if (rem == 1) asm volatile("s_waitcnt vmcnt(0)" ::: "memory");
        asm volatile("" ::: "memory");
        if (rem > 0) __builtin_amdgcn_s_barrier();
        asm volatile("" ::: "memory");
    }

#pragma unroll
    for (int hh = 0; hh < 2; ++hh) {
        float inv[4];
#pragma unroll
        for (int j = 0; j < 4; ++j) {
            float d = dsum[hh][j];
            d += __shfl_xor(d, 1, 64);
            d += __shfl_xor(d, 2, 64);
            d += __shfl_xor(d, 4, 64);
            d += __shfl_xor(d, 8, 64);
            inv[j] = 1.f / (d + NORM_EPS);
        }
#pragma unroll
        for (int nq = 0; nq < 8; ++nq)
#pragma unroll
            for (int j = 0; j < 4; ++j) {
                const int row = t0 + wid * 16 + (lane >> 4) * 4 + j;
                out[(size_t)row * (NH * HD) + (2 * h + hh) * HD + nq * 16 + (lane & 15)] =
                    (_Float16)(acc_o[hh][nq][j] * inv[j]);
            }
    }
}

// ---------------------------------------------------------------------------
extern "C" void kernel_launch(void* const* d_in, const int* in_sizes, int n_in,
                              void* d_out, int out_size, void* d_ws, size_t ws_size,
                              hipStream_t stream) {
    const float* hs    = (const float*)d_in[0];
    const float* qkv_w = (const float*)d_in[1];
    const float* g_w   = (const float*)d_in[2];
    const float* o_w   = (const float*)d_in[3];
    const float* q_nw  = (const float*)d_in[4];
    const float* k_nw  = (const float*)d_in[5];
    const int*   pos   = (const int*)d_in[6];

    _Float16* hs16   = (_Float16*)d_ws;                      // 3072*2048 (reused for attn out)
    _Float16* qkvw16 = hs16 + (size_t)T_LEN * HID_DIM;       // 4096*2048
    _Float16* ow16   = qkvw16 + (size_t)QKV_COLS * HID_DIM;  // 2048*2048
    _Float16* qkv16  = ow16 + (size_t)HID_DIM * HID_DIM;     // 3072*4096 (v region unused)
    _Float16* vtb    = qkv16 + (size_t)T_LEN * QKV_COLS;     // 1024*3072 (V transposed)
    float* gate = (float*)(vtb + (size_t)NKV * HD * T_LEN);
    float* cgb  = gate + (size_t)T_LEN * NKV;
    float2* rope_tab = (float2*)(cgb + (size_t)T_LEN * NKV); // 3072*64*8B

    constexpr int NA = QKV_COLS * HID_DIM;   // 8388608
    constexpr int NB = HID_DIM * HID_DIM;    // 4194304
    cast_gate<<<T_LEN, 256, 0, stream>>>(hs, g_w, pos, hs16, gate, rope_tab);
    cast_two<<<(NA + NB) / 2048, 256, 0, stream>>>(qkv_w, o_w, qkvw16, ow16, NA, NA + NB);
    cumsum_kernel<<<NKV, 1024, 0, stream>>>(gate, cgb);
    // qkv projection: 192x256 tiles (r9 config), 16x16 = 256 blocks;
    // RMSNorm+RoPE fused into epilogue; v written transposed into vtb
    gemm_mph<T_LEN, QKV_COLS, HID_DIM, 192, 256, 2, 4, 2, _Float16, true, true>
        <<<(T_LEN / 192) * (QKV_COLS / 256), 512, 0, stream>>>(
            hs16, qkvw16, qkv16, vtb, q_nw, k_nw, rope_tab);
    // pipelined retention: 48 x 8 blocks, 2 q-heads per block
    attn_mfma2<<<dim3(T_LEN / AQT, NKV), 256, 0, stream>>>(qkv16, vtb, cgb, hs16);
    // output projection: 192x128 tiles, 16x16 = 256 blocks (2 blocks/CU)
    gemm_mph<T_LEN, HID_DIM, HID_DIM, 192, 128, 4, 2, 4, float, false, false>
        <<<(T_LEN / 192) * (HID_DIM / 128), 512, 0, stream>>>(
            hs16, ow16, (float*)d_out, nullptr, nullptr, nullptr, nullptr);
    (void)in_sizes; (void)n_in; (void)out_size; (void)ws_size;
}

// Round 12
// 164.921 us; speedup vs baseline: 1.3245x; 1.1064x over previous
//
#include <hip/hip_runtime.h>
#include <math.h>

#define T_LEN 3072
#define HID_DIM 2048
#define NH 16
#define NKV 8
#define HD 128
#define QKV_COLS ((NH + 2 * NKV) * HD)   // 4096
#define V_OFF (NH * HD + NKV * HD)       // 3072
#define RMS_EPS 1e-6f
#define NORM_EPS 1e-6f
#define THETA 10000.0f
#define SCALE 0.08838834764831845f       // 128^-0.5

#define BAND 256   // exp(-0.65*256)=e^-167 -> exactly 0 in f32; validated round 1
#define AQT 64     // q rows per attn block

typedef __attribute__((ext_vector_type(8))) _Float16 f16x8;
typedef __attribute__((ext_vector_type(4))) float f32x4;

__device__ __forceinline__ void gload_lds16(const void* g, void* l) {
    __builtin_amdgcn_global_load_lds((const __attribute__((address_space(1))) void*)g,
                                     (__attribute__((address_space(3))) void*)l, 16, 0, 0);
}
__device__ __forceinline__ void gload_lds4(const void* g, void* l) {
    __builtin_amdgcn_global_load_lds((const __attribute__((address_space(1))) void*)g,
                                     (__attribute__((address_space(3))) void*)l, 4, 0, 0);
}

#define VMCNT_I(n) asm volatile("s_waitcnt vmcnt(" #n ")" ::: "memory")

// ---------------------------------------------------------------------------
// m201-granularity f16 MFMA GEMM (schedule validated r9/r10; 0 conflicts).
// FUSE_NR (qkv, BM=192 BN=256): column mapping permuted so each wave holds
// the (d, d+64) rope pair of each head in-register: col(ni) = (ni>>1)*128 +
// (ni&1)*64 + wn*16. RMSNorm cross-wave reduce via 6KB ssbuf (broadcast
// float4 reads); rope fully in-register from rope_tab (24 loads/thread).
// V tiles write transposed into vt.
// ---------------------------------------------------------------------------
template <int M, int N, int K, int BM, int BN, int WM, int WN, int WPE,
          typename OutT, bool SPLIT_V, bool FUSE_NR>
__global__ __launch_bounds__(512, WPE) void gemm_mph(const _Float16* __restrict__ A,
                                                     const _Float16* __restrict__ Bp,
                                                     OutT* __restrict__ C,
                                                     _Float16* __restrict__ vt,
                                                     const float* __restrict__ qw,
                                                     const float* __restrict__ kw,
                                                     const float2* __restrict__ rope_tab) {
    constexpr int MI = BM / WM / 16;
    constexpr int NGROUP = (MI >= 6) ? 2 : 1;
    constexpr int GSZ = MI / NGROUP;
    constexpr int NI = BN / WN / 16;
    constexpr int NT = K / 64;
    constexpr int NX = N / BN;
    constexpr int HALF = (BM + BN) * 64;
    constexpr int FULL = HALF / 8192;
    constexpr int REM = HALF - FULL * 8192;
    constexpr int NISS = FULL + (REM ? 2 : 0);
    static_assert(REM == 0 || REM == 4096, "staging remainder must be 4KB");
    static_assert(!FUSE_NR || (BN == 256 && WN == 4), "FUSE_NR needs BN=256, WN=4");
    __shared__ char lds[2 * 2 * HALF];

    const int tid = threadIdx.x, lane = tid & 63, wid = tid >> 6;
    const int wm = wid / WN, wn = wid % WN;
    const int q8 = gridDim.x >> 3;
    const int sw = (blockIdx.x & 7) * q8 + (blockIdx.x >> 3);
    const int brow = (sw / NX) * BM, bcol = (sw % NX) * BN;

    // column-within-tile of B fragment ni (permuted when FUSE_NR)
    auto colOf = [&](int ni) {
        if constexpr (FUSE_NR) return (ni >> 1) * 128 + (ni & 1) * 64 + wn * 16;
        else                   return wn * (BN / WN) + ni * 16;
    };

    auto stage_half = [&](int t, int kh) {
        char* hb = lds + (size_t)((t & 1) * 2 + kh) * HALF;
        const int k0 = t * 64 + kh * 32;
#pragma unroll
        for (int j = 0; j < FULL; ++j) {
            const int L = j * 8192 + tid * 16;
            if (L < BM * 64) {
                const int r = L >> 6;
                const int c = ((L >> 4) & 3) ^ ((r >> 1) & 3);
                gload_lds16(A + (size_t)(brow + r) * K + k0 + c * 8, hb + L);
            } else {
                const int Lb = L - BM * 64;
                const int r = Lb >> 6;
                const int c = ((Lb >> 4) & 3) ^ ((r >> 1) & 3);
                gload_lds16(Bp + (size_t)(bcol + r) * K + k0 + c * 8, hb + L);
            }
        }
        if constexpr (REM != 0) {
#pragma unroll
            for (int j = 0; j < 2; ++j) {
                const int L = FULL * 8192 + j * 2048 + (tid >> 6) * 256 + (tid & 63) * 4;
                const int Lb = L - BM * 64;
                const int r = Lb >> 6;
                const int wb = Lb & 63;
                const int c = (wb >> 4) ^ ((r >> 1) & 3);
                gload_lds4(Bp + (size_t)(bcol + r) * K + k0 + c * 8 + ((wb & 15) >> 1),
                           hb + (L & ~255));
            }
        }
    };
    auto wait_n = [&]() {
        if constexpr (NISS == 5) VMCNT_I(5);
        else if constexpr (NISS == 4) VMCNT_I(4);
        else VMCNT_I(3);
    };

    f32x4 acc[MI][NI];
#pragma unroll
    for (int mi = 0; mi < MI; ++mi)
#pragma unroll
        for (int ni = 0; ni < NI; ++ni) acc[mi][ni] = (f32x4){0.f, 0.f, 0.f, 0.f};

    stage_half(0, 0);
    stage_half(0, 1);
    wait_n();
    asm volatile("" ::: "memory");
    __builtin_amdgcn_s_barrier();
    asm volatile("" ::: "memory");

    for (int t = 0; t < NT; ++t) {
        const char* buf = lds + (size_t)(t & 1) * 2 * HALF;
#pragma unroll
        for (int kh = 0; kh < 2; ++kh) {
            const char* ab = buf + kh * HALF;
            const char* bb = ab + BM * 64;
            f16x8 bf[NI];
#pragma unroll
            for (int g = 0; g < NGROUP; ++g) {
                if (g == 0) {
#pragma unroll
                    for (int ni = 0; ni < NI; ++ni) {
                        const int r = colOf(ni) + (lane & 15);
                        bf[ni] = *reinterpret_cast<const f16x8*>(
                            bb + r * 64 + ((((lane >> 4)) ^ ((r >> 1) & 3)) << 4));
                    }
                }
                f16x8 af[GSZ];
#pragma unroll
                for (int m = 0; m < GSZ; ++m) {
                    const int r = wm * (BM / WM) + (g * GSZ + m) * 16 + (lane & 15);
                    af[m] = *reinterpret_cast<const f16x8*>(
                        ab + r * 64 + ((((lane >> 4)) ^ ((r >> 1) & 3)) << 4));
                }
                if (g == 0 && t + 1 < NT) stage_half(t + 1, kh);
                asm volatile("" ::: "memory");
                __builtin_amdgcn_s_barrier();
                asm volatile("s_waitcnt lgkmcnt(0)" ::: "memory");
                __builtin_amdgcn_sched_barrier(0);
                __builtin_amdgcn_s_setprio(1);
#pragma unroll
                for (int m = 0; m < GSZ; ++m)
#pragma unroll
                    for (int ni = 0; ni < NI; ++ni)
                        acc[g * GSZ + m][ni] = __builtin_amdgcn_mfma_f32_16x16x32_f16(
                            af[m], bf[ni], acc[g * GSZ + m][ni], 0, 0, 0);
                __builtin_amdgcn_s_setprio(0);
                if (g == NGROUP - 1) {
                    if (kh == 0) {
                        if (t == NT - 1) VMCNT_I(0);
                        else wait_n();
                    } else if (t + 1 < NT) {
                        wait_n();
                    }
                }
                asm volatile("" ::: "memory");
                __builtin_amdgcn_s_barrier();
                asm volatile("" ::: "memory");
            }
        }
    }

    if constexpr (FUSE_NR) {
        if (bcol >= V_OFF) {   // V tile -> transposed write (permuted cols)
#pragma unroll
            for (int mi = 0; mi < MI; ++mi)
#pragma unroll
                for (int ni = 0; ni < NI; ++ni) {
                    const int col = bcol - V_OFF + colOf(ni) + (lane & 15);
                    const int rb = brow + wm * (BM / WM) + mi * 16 + (lane >> 4) * 4;
#pragma unroll
                    for (int j = 0; j < 4; ++j)
                        vt[(size_t)col * M + rb + j] = (_Float16)acc[mi][ni][j];
                }
        } else {               // q/k tile -> fused RMSNorm + RoPE, all in-register
            const bool is_q = (bcol < NH * HD);
            const float* nw = is_q ? qw : kw;
            const float sc = is_q ? SCALE : 1.0f;
            float* ssbuf = (float*)lds;          // [wm:2][head:2][row:96][wn:4]
            const int fidx = wn * 16 + (lane & 15);
            const float w0 = nw[fidx], w1 = nw[64 + fidx];
            // partial SS per (head,row) over this wave's 32 cols of the head
#pragma unroll
            for (int hl = 0; hl < 2; ++hl)
#pragma unroll
                for (int mi = 0; mi < MI; ++mi)
#pragma unroll
                    for (int j = 0; j < 4; ++j) {
                        float v0 = acc[mi][hl * 2 + 0][j];
                        float v1 = acc[mi][hl * 2 + 1][j];
                        float s = v0 * v0 + v1 * v1;
                        s += __shfl_xor(s, 1, 64);
                        s += __shfl_xor(s, 2, 64);
                        s += __shfl_xor(s, 4, 64);
                        s += __shfl_xor(s, 8, 64);
                        if ((lane & 15) == 0) {
                            const int rl = mi * 16 + (lane >> 4) * 4 + j;
                            ssbuf[(((wm * 2 + hl) * 96 + rl) << 2) + wn] = s;
                        }
                    }
            __syncthreads();
#pragma unroll
            for (int mi = 0; mi < MI; ++mi)
#pragma unroll
                for (int j = 0; j < 4; ++j) {
                    const int rl = mi * 16 + (lane >> 4) * 4 + j;
                    const int trow = brow + wm * (BM / WM) + rl;
                    float2 cssn = rope_tab[(size_t)trow * 64 + fidx];
#pragma unroll
                    for (int hl = 0; hl < 2; ++hl) {
                        float4 sv = *reinterpret_cast<const float4*>(
                            &ssbuf[((wm * 2 + hl) * 96 + rl) << 2]);   // broadcast read
                        float rs = rsqrtf((sv.x + sv.y + sv.z + sv.w) * (1.0f / HD) + RMS_EPS);
                        float v0 = acc[mi][hl * 2 + 0][j] * rs * w0;
                        float v1 = acc[mi][hl * 2 + 1][j] * rs * w1;
                        float o0 = (v0 * cssn.x - v1 * cssn.y) * sc;
                        float o1 = (v1 * cssn.x + v0 * cssn.y) * sc;
                        const size_t base = (size_t)trow * N + bcol + hl * 128 + fidx;
                        C[base] = (OutT)o0;
                        C[base + 64] = (OutT)o1;
                    }
                }
        }
    } else if (SPLIT_V && bcol >= V_OFF) {
#pragma unroll
        for (int mi = 0; mi < MI; ++mi)
#pragma unroll
            for (int ni = 0; ni < NI; ++ni) {
                const int col = bcol - V_OFF + wn * (BN / WN) + ni * 16 + (lane & 15);
                const int rb = brow + wm * (BM / WM) + mi * 16 + (lane >> 4) * 4;
#pragma unroll
                for (int j = 0; j < 4; ++j)
                    vt[(size_t)col * M + rb + j] = (_Float16)acc[mi][ni][j];
            }
    } else {
#pragma unroll
        for (int mi = 0; mi < MI; ++mi)
#pragma unroll
            for (int ni = 0; ni < NI; ++ni) {
                const int col = bcol + wn * (BN / WN) + ni * 16 + (lane & 15);
                const int rb = brow + wm * (BM / WM) + mi * 16 + (lane >> 4) * 4;
#pragma unroll
                for (int j = 0; j < 4; ++j)
                    C[(size_t)(rb + j) * N + col] = (OutT)acc[mi][ni][j];
            }
    }
}

// ---------------------------------------------------------------------------
// Merged weight cast: [0, na) from a, [na, na+nb) from b. na % 8 == 0.
// ---------------------------------------------------------------------------
__global__ __launch_bounds__(256) void cast_two(const float* __restrict__ a,
                                                const float* __restrict__ b,
                                                _Float16* __restrict__ oa,
                                                _Float16* __restrict__ ob,
                                                int na, int ntot) {
    const int i = (blockIdx.x * 256 + threadIdx.x) * 8;
    if (i >= ntot) return;
    const float* src = (i < na) ? a + i : b + (i - na);
    _Float16* dst = (i < na) ? oa + i : ob + (i - na);
    float4 x = *reinterpret_cast<const float4*>(src);
    float4 y = *reinterpret_cast<const float4*>(src + 4);
    f16x8 o;
    o[0] = (_Float16)x.x; o[1] = (_Float16)x.y; o[2] = (_Float16)x.z; o[3] = (_Float16)x.w;
    o[4] = (_Float16)y.x; o[5] = (_Float16)y.y; o[6] = (_Float16)y.z; o[7] = (_Float16)y.w;
    *reinterpret_cast<f16x8*>(dst) = o;
}

// ---------------------------------------------------------------------------
// Fused: hs cast, gate = log_sigmoid(hs . g_w), rope cos/sin table.
// ---------------------------------------------------------------------------
__global__ __launch_bounds__(256) void cast_gate(const float* __restrict__ hs,
                                                 const float* __restrict__ g_w,
                                                 const int* __restrict__ pos,
                                                 _Float16* __restrict__ hs16,
                                                 float* __restrict__ gate,
                                                 float2* __restrict__ rope_tab) {
    const int t = blockIdx.x;
    const int tid = threadIdx.x, lane = tid & 63, wave = tid >> 6;
    const int i = tid * 8;
    const float* row = hs + (size_t)t * HID_DIM;
    float4 a = *reinterpret_cast<const float4*>(&row[i]);
    float4 b = *reinterpret_cast<const float4*>(&row[i + 4]);
    f16x8 o;
    o[0] = (_Float16)a.x; o[1] = (_Float16)a.y; o[2] = (_Float16)a.z; o[3] = (_Float16)a.w;
    o[4] = (_Float16)b.x; o[5] = (_Float16)b.y; o[6] = (_Float16)b.z; o[7] = (_Float16)b.w;
    *reinterpret_cast<f16x8*>(&hs16[(size_t)t * HID_DIM + i]) = o;

    if (tid < 64) {
        float inv_freq = powf(THETA, -(float)tid * (1.0f / 64.0f));
        float ang = (float)pos[t] * inv_freq;
        float sn, cs;
        sincosf(ang, &sn, &cs);
        rope_tab[(size_t)t * 64 + tid] = make_float2(cs, sn);
    }

    float s[NKV];
#pragma unroll
    for (int h = 0; h < NKV; ++h) {
        const float4 wa = *reinterpret_cast<const float4*>(&g_w[(size_t)h * HID_DIM + i]);
        const float4 wb = *reinterpret_cast<const float4*>(&g_w[(size_t)h * HID_DIM + i + 4]);
        s[h] = a.x * wa.x + a.y * wa.y + a.z * wa.z + a.w * wa.w
             + b.x * wb.x + b.y * wb.y + b.z * wb.z + b.w * wb.w;
    }
#pragma unroll
    for (int off = 32; off > 0; off >>= 1)
#pragma unroll
        for (int h = 0; h < NKV; ++h) s[h] += __shfl_down(s[h], off, 64);
    __shared__ float red[4][NKV];
    if (lane == 0)
#pragma unroll
        for (int h = 0; h < NKV; ++h) red[wave][h] = s[h];
    __syncthreads();
    if (tid < NKV) {
        float x = red[0][tid] + red[1][tid] + red[2][tid] + red[3][tid];
        float ls = fminf(x, 0.f) - log1pf(expf(-fabsf(x)));
        gate[(size_t)t * NKV + tid] = ls;
    }
}

// ---------------------------------------------------------------------------
__global__ __launch_bounds__(1024) void cumsum_kernel(const float* __restrict__ gate,
                                                      float* __restrict__ cg) {
    const int h = blockIdx.x;
    const int tid = threadIdx.x;
    float v0 = gate[(size_t)(tid * 3 + 0) * NKV + h];
    float v1 = gate[(size_t)(tid * 3 + 1) * NKV + h];
    float v2 = gate[(size_t)(tid * 3 + 2) * NKV + h];
    float p0 = v0, p1 = v0 + v1, p2 = v0 + v1 + v2;
    __shared__ float s[1024];
    s[tid] = p2;
    __syncthreads();
    float sum = p2;
    for (int off = 1; off < 1024; off <<= 1) {
        float add = (tid >= off) ? s[tid - off] : 0.f;
        __syncthreads();
        sum += add;
        s[tid] = sum;
        __syncthreads();
    }
    float base = sum - p2;
    cg[(size_t)(tid * 3 + 0) * NKV + h] = base + p0;
    cg[(size_t)(tid * 3 + 1) * NKV + h] = base + p1;
    cg[(size_t)(tid * 3 + 2) * NKV + h] = base + p2;
}

// ---------------------------------------------------------------------------
// Pipelined MFMA banded retention (verified round 6, unchanged).
// ---------------------------------------------------------------------------
__global__ __launch_bounds__(256, 2) void attn_mfma2(const _Float16* __restrict__ qkv,
                                                     const _Float16* __restrict__ vt,
                                                     const float* __restrict__ cg,
                                                     _Float16* __restrict__ out) {
    const int h = blockIdx.y;
    const int t0 = blockIdx.x * AQT;
    const int tid = threadIdx.x, lane = tid & 63, wid = tid >> 6;

    __shared__ char buf[4][16384];
    __shared__ char WsB[2][4096];
    __shared__ float cgS[BAND + AQT];

    const int s_lo = (t0 >= BAND) ? t0 - BAND : 0;
    const int NT = (t0 + AQT - s_lo) >> 5;
    const int span = t0 + AQT - s_lo;

    for (int i = tid; i < span; i += 256)
        cgS[i] = cg[(size_t)(s_lo + i) * NKV + h];

    f16x8 qa[2][4];
    {
        const int qrow = t0 + wid * 16 + (lane & 15);
#pragma unroll
        for (int hh = 0; hh < 2; ++hh) {
            const _Float16* qp = qkv + (size_t)qrow * QKV_COLS + (2 * h + hh) * HD + (lane >> 4) * 8;
#pragma unroll
            for (int kq = 0; kq < 4; ++kq)
                qa[hh][kq] = *reinterpret_cast<const f16x8*>(qp + kq * 32);
        }
    }

    auto stage = [&](int t) {
        const int s0 = s_lo + t * 32;
        char* kd = (char*)buf + (size_t)(t & 3) * 16384;
        char* vd = kd + 8192;
#pragma unroll
        for (int i = 0; i < 2; ++i) {
            const int r = i * 16 + (tid >> 4);
            const int celem = (((tid & 15) * 16) ^ ((r & 7) << 4)) >> 1;
            gload_lds16(qkv + (size_t)(s0 + r) * QKV_COLS + NH * HD + h * HD + celem,
                        kd + i * 4096 + tid * 16);
        }
#pragma unroll
        for (int i = 0; i < 2; ++i) {
            const int d = i * 64 + (tid >> 2);
            const int key = (d ^ (d >> 2)) & 3;
            gload_lds16(vt + (size_t)(h * HD + d) * T_LEN + s0 + 8 * ((tid & 3) ^ key),
                        vd + i * 4096 + tid * 16);
        }
    };

    stage(0); stage(1); stage(2);
    __syncthreads();

    float cqr[4];
#pragma unroll
    for (int j = 0; j < 4; ++j)
        cqr[j] = cgS[(span - AQT) + wid * 16 + (lane >> 4) * 4 + j];

    f32x4 acc_o[2][8];
#pragma unroll
    for (int hh = 0; hh < 2; ++hh)
#pragma unroll
        for (int nq = 0; nq < 8; ++nq) acc_o[hh][nq] = (f32x4){0.f, 0.f, 0.f, 0.f};
    float dsum[2][4] = {{0.f, 0.f, 0.f, 0.f}, {0.f, 0.f, 0.f, 0.f}};

    for (int t = 0; t < NT; ++t) {
        if (t + 3 < NT) stage(t + 3);
        const char* kbase = (const char*)buf + (size_t)(t & 3) * 16384;
        const char* vbase = kbase + 8192;
        const int s0 = s_lo + t * 32;

        f16x8 kf[2][4];
#pragma unroll
        for (int c = 0; c < 2; ++c) {
            const int rr = c * 16 + (lane & 15);
#pragma unroll
            for (int kq = 0; kq < 4; ++kq) {
                const int bi = (kq * 64 + (lane >> 4) * 16) ^ ((rr & 7) << 4);
                kf[c][kq] = *reinterpret_cast<const f16x8*>(kbase + rr * 256 + bi);
            }
        }
        float csv[2];
        csv[0] = cgS[t * 32 + (lane & 15)];
        csv[1] = cgS[t * 32 + 16 + (lane & 15)];

#pragma unroll
        for (int hh = 0; hh < 2; ++hh) {
            f32x4 accs[2];
            accs[0] = (f32x4){0.f, 0.f, 0.f, 0.f};
            accs[1] = (f32x4){0.f, 0.f, 0.f, 0.f};
#pragma unroll
            for (int c = 0; c < 2; ++c)
#pragma unroll
                for (int kq = 0; kq < 4; ++kq)
                    accs[c] = __builtin_amdgcn_mfma_f32_16x16x32_f16(
                        qa[hh][kq], kf[c][kq], accs[c], 0, 0, 0);
#pragma unroll
            for (int c = 0; c < 2; ++c) {
                const int sg = s0 + c * 16 + (lane & 15);
#pragma unroll
                for (int j = 0; j < 4; ++j) {
                    const int qg = t0 + wid * 16 + (lane >> 4) * 4 + j;
                    const float sv = accs[c][j];
                    const float w = (sg <= qg) ? __expf(cqr[j] - csv[c]) * sv * sv : 0.f;
                    const _Float16 wh = (_Float16)w;
                    dsum[hh][j] += (float)wh;
                    const int q = wid * 16 + (lane >> 4) * 4 + j;
                    const int addr = q * 64 +
                        ((2 * (c * 16 + (lane & 15))) ^ (((q ^ (q >> 2)) & 3) << 4));
                    *(_Float16*)(WsB[hh] + addr) = wh;
                }
            }
        }
        asm volatile("s_waitcnt lgkmcnt(0)" ::: "memory");
        __builtin_amdgcn_sched_barrier(0);

        const int qr = wid * 16 + (lane & 15);
        const int wb = qr * 64 + (((lane >> 4) * 16) ^ (((qr ^ (qr >> 2)) & 3) << 4));
        f16x8 wf0 = *reinterpret_cast<const f16x8*>(WsB[0] + wb);
        f16x8 wf1 = *reinterpret_cast<const f16x8*>(WsB[1] + wb);
        f16x8 vf[8];
#pragma unroll
        for (int nq = 0; nq < 8; ++nq) {
            const int dr = nq * 16 + (lane & 15);
            const int vb = dr * 64 + (((lane >> 4) * 16) ^ (((dr ^ (dr >> 2)) & 3) << 4));
            vf[nq] = *reinterpret_cast<const f16x8*>(vbase + vb);
        }
        __builtin_amdgcn_s_setprio(1);
#pragma unroll
        for (int nq = 0; nq < 8; ++nq) {
            acc_o[0][nq] = __builtin_amdgcn_mfma_f32_16x16x32_f16(wf0, vf[nq], acc_o[0][nq], 0, 0, 0);
            acc_o[1][nq] = __builtin_amdgcn_mfma_f32_16x16x32_f16(wf1, vf[nq], acc_o[1][nq], 0, 0, 0);
        }
        __builtin_amdgcn_s_setprio(0);

        const int rem = NT - 1 - t;
        if (rem >= 3)      asm volatile("s_waitcnt vmcnt(8)" ::: "memory");
        else if (rem == 2) asm volatile("s_waitcnt vmcnt(4)" ::: "memory");
        else if (rem == 1) asm volatile("s_waitcnt vmcnt(0)" ::: "memory");
        asm volatile("" ::: "memory");
        if (rem > 0) __builtin_amdgcn_s_barrier();
        asm volatile("" ::: "memory");
    }

#pragma unroll
    for (int hh = 0; hh < 2; ++hh) {
        float inv[4];
#pragma unroll
        for (int j = 0; j < 4; ++j) {
            float d = dsum[hh][j];
            d += __shfl_xor(d, 1, 64);
            d += __shfl_xor(d, 2, 64);
            d += __shfl_xor(d, 4, 64);
            d += __shfl_xor(d, 8, 64);
            inv[j] = 1.f / (d + NORM_EPS);
        }
#pragma unroll
        for (int nq = 0; nq < 8; ++nq)
#pragma unroll
            for (int j = 0; j < 4; ++j) {
                const int row = t0 + wid * 16 + (lane >> 4) * 4 + j;
                out[(size_t)row * (NH * HD) + (2 * h + hh) * HD + nq * 16 + (lane & 15)] =
                    (_Float16)(acc_o[hh][nq][j] * inv[j]);
            }
    }
}

// ---------------------------------------------------------------------------
extern "C" void kernel_launch(void* const* d_in, const int* in_sizes, int n_in,
                              void* d_out, int out_size, void* d_ws, size_t ws_size,
                              hipStream_t stream) {
    const float* hs    = (const float*)d_in[0];
    const float* qkv_w = (const float*)d_in[1];
    const float* g_w   = (const float*)d_in[2];
    const float* o_w   = (const float*)d_in[3];
    const float* q_nw  = (const float*)d_in[4];
    const float* k_nw  = (const float*)d_in[5];
    const int*   pos   = (const int*)d_in[6];

    _Float16* hs16   = (_Float16*)d_ws;                      // 3072*2048 (reused for attn out)
    _Float16* qkvw16 = hs16 + (size_t)T_LEN * HID_DIM;       // 4096*2048
    _Float16* ow16   = qkvw16 + (size_t)QKV_COLS * HID_DIM;  // 2048*2048
    _Float16* qkv16  = ow16 + (size_t)HID_DIM * HID_DIM;     // 3072*4096 (v region unused)
    _Float16* vtb    = qkv16 + (size_t)T_LEN * QKV_COLS;     // 1024*3072 (V transposed)
    float* gate = (float*)(vtb + (size_t)NKV * HD * T_LEN);
    float* cgb  = gate + (size_t)T_LEN * NKV;
    float2* rope_tab = (float2*)(cgb + (size_t)T_LEN * NKV); // 3072*64*8B

    constexpr int NA = QKV_COLS * HID_DIM;   // 8388608
    constexpr int NB = HID_DIM * HID_DIM;    // 4194304
    cast_gate<<<T_LEN, 256, 0, stream>>>(hs, g_w, pos, hs16, gate, rope_tab);
    cast_two<<<(NA + NB) / 2048, 256, 0, stream>>>(qkv_w, o_w, qkvw16, ow16, NA, NA + NB);
    cumsum_kernel<<<NKV, 1024, 0, stream>>>(gate, cgb);
    // qkv projection: 192x256 tiles, 256 blocks; RMSNorm+RoPE fused in-register
    gemm_mph<T_LEN, QKV_COLS, HID_DIM, 192, 256, 2, 4, 2, _Float16, true, true>
        <<<(T_LEN / 192) * (QKV_COLS / 256), 512, 0, stream>>>(
            hs16, qkvw16, qkv16, vtb, q_nw, k_nw, rope_tab);
    // pipelined retention: 48 x 8 blocks, 2 q-heads per block
    attn_mfma2<<<dim3(T_LEN / AQT, NKV), 256, 0, stream>>>(qkv16, vtb, cgb, hs16);
    // output projection: 192x128 tiles, 16x16 = 256 blocks (2 blocks/CU)
    gemm_mph<T_LEN, HID_DIM, HID_DIM, 192, 128, 4, 2, 4, float, false, false>
        <<<(T_LEN / 192) * (HID_DIM / 128), 512, 0, stream>>>(
            hs16, ow16, (float*)d_out, nullptr, nullptr, nullptr, nullptr);
    (void)in_sizes; (void)n_in; (void)out_size; (void)ws_size;
}

// Round 13
// 155.926 us; speedup vs baseline: 1.4009x; 1.0577x over previous
//
#include <hip/hip_runtime.h>
#include <math.h>

#define T_LEN 3072
#define HID_DIM 2048
#define NH 16
#define NKV 8
#define HD 128
#define QKV_COLS ((NH + 2 * NKV) * HD)   // 4096
#define V_OFF (NH * HD + NKV * HD)       // 3072
#define RMS_EPS 1e-6f
#define NORM_EPS 1e-6f
#define THETA 10000.0f
#define SCALE 0.08838834764831845f       // 128^-0.5

#define BAND 256   // exp(-0.65*256)=e^-167 -> exactly 0 in f32; validated round 1
#define AQT 64     // q rows per attn block

typedef __attribute__((ext_vector_type(8))) _Float16 f16x8;
typedef __attribute__((ext_vector_type(4))) float f32x4;

__device__ __forceinline__ void gload_lds16(const void* g, void* l) {
    __builtin_amdgcn_global_load_lds((const __attribute__((address_space(1))) void*)g,
                                     (__attribute__((address_space(3))) void*)l, 16, 0, 0);
}
__device__ __forceinline__ void gload_lds4(const void* g, void* l) {
    __builtin_amdgcn_global_load_lds((const __attribute__((address_space(1))) void*)g,
                                     (__attribute__((address_space(3))) void*)l, 4, 0, 0);
}

#define VMCNT_I(n) asm volatile("s_waitcnt vmcnt(" #n ")" ::: "memory")

// ---------------------------------------------------------------------------
// m201-granularity f16 MFMA GEMM (schedule validated r9-r12; 0 conflicts).
// FUSE_NR (qkv, BM=192 BN=256): permuted column map puts each head's rope
// pair (d, d+64) in-register; RMSNorm via 6KB ssbuf; validated r12 (70us,
// absmax 2.4e-4). V tiles write transposed into vt.
// ---------------------------------------------------------------------------
template <int M, int N, int K, int BM, int BN, int WM, int WN, int WPE,
          typename OutT, bool SPLIT_V, bool FUSE_NR>
__global__ __launch_bounds__(512, WPE) void gemm_mph(const _Float16* __restrict__ A,
                                                     const _Float16* __restrict__ Bp,
                                                     OutT* __restrict__ C,
                                                     _Float16* __restrict__ vt,
                                                     const float* __restrict__ qw,
                                                     const float* __restrict__ kw,
                                                     const float2* __restrict__ rope_tab) {
    constexpr int MI = BM / WM / 16;
    constexpr int NGROUP = (MI >= 6) ? 2 : 1;
    constexpr int GSZ = MI / NGROUP;
    constexpr int NI = BN / WN / 16;
    constexpr int NT = K / 64;
    constexpr int NX = N / BN;
    constexpr int HALF = (BM + BN) * 64;
    constexpr int FULL = HALF / 8192;
    constexpr int REM = HALF - FULL * 8192;
    constexpr int NISS = FULL + (REM ? 2 : 0);
    static_assert(REM == 0 || REM == 4096, "staging remainder must be 4KB");
    static_assert(!FUSE_NR || (BN == 256 && WN == 4), "FUSE_NR needs BN=256, WN=4");
    __shared__ char lds[2 * 2 * HALF];

    const int tid = threadIdx.x, lane = tid & 63, wid = tid >> 6;
    const int wm = wid / WN, wn = wid % WN;
    const int q8 = gridDim.x >> 3;
    const int sw = (blockIdx.x & 7) * q8 + (blockIdx.x >> 3);
    const int brow = (sw / NX) * BM, bcol = (sw % NX) * BN;

    auto colOf = [&](int ni) {
        if constexpr (FUSE_NR) return (ni >> 1) * 128 + (ni & 1) * 64 + wn * 16;
        else                   return wn * (BN / WN) + ni * 16;
    };

    auto stage_half = [&](int t, int kh) {
        char* hb = lds + (size_t)((t & 1) * 2 + kh) * HALF;
        const int k0 = t * 64 + kh * 32;
#pragma unroll
        for (int j = 0; j < FULL; ++j) {
            const int L = j * 8192 + tid * 16;
            if (L < BM * 64) {
                const int r = L >> 6;
                const int c = ((L >> 4) & 3) ^ ((r >> 1) & 3);
                gload_lds16(A + (size_t)(brow + r) * K + k0 + c * 8, hb + L);
            } else {
                const int Lb = L - BM * 64;
                const int r = Lb >> 6;
                const int c = ((Lb >> 4) & 3) ^ ((r >> 1) & 3);
                gload_lds16(Bp + (size_t)(bcol + r) * K + k0 + c * 8, hb + L);
            }
        }
        if constexpr (REM != 0) {
#pragma unroll
            for (int j = 0; j < 2; ++j) {
                const int L = FULL * 8192 + j * 2048 + (tid >> 6) * 256 + (tid & 63) * 4;
                const int Lb = L - BM * 64;
                const int r = Lb >> 6;
                const int wb = Lb & 63;
                const int c = (wb >> 4) ^ ((r >> 1) & 3);
                gload_lds4(Bp + (size_t)(bcol + r) * K + k0 + c * 8 + ((wb & 15) >> 1),
                           hb + (L & ~255));
            }
        }
    };
    auto wait_n = [&]() {
        if constexpr (NISS == 5) VMCNT_I(5);
        else if constexpr (NISS == 4) VMCNT_I(4);
        else VMCNT_I(3);
    };

    f32x4 acc[MI][NI];
#pragma unroll
    for (int mi = 0; mi < MI; ++mi)
#pragma unroll
        for (int ni = 0; ni < NI; ++ni) acc[mi][ni] = (f32x4){0.f, 0.f, 0.f, 0.f};

    stage_half(0, 0);
    stage_half(0, 1);
    wait_n();
    asm volatile("" ::: "memory");
    __builtin_amdgcn_s_barrier();
    asm volatile("" ::: "memory");

    for (int t = 0; t < NT; ++t) {
        const char* buf = lds + (size_t)(t & 1) * 2 * HALF;
#pragma unroll
        for (int kh = 0; kh < 2; ++kh) {
            const char* ab = buf + kh * HALF;
            const char* bb = ab + BM * 64;
            f16x8 bf[NI];
#pragma unroll
            for (int g = 0; g < NGROUP; ++g) {
                if (g == 0) {
#pragma unroll
                    for (int ni = 0; ni < NI; ++ni) {
                        const int r = colOf(ni) + (lane & 15);
                        bf[ni] = *reinterpret_cast<const f16x8*>(
                            bb + r * 64 + ((((lane >> 4)) ^ ((r >> 1) & 3)) << 4));
                    }
                }
                f16x8 af[GSZ];
#pragma unroll
                for (int m = 0; m < GSZ; ++m) {
                    const int r = wm * (BM / WM) + (g * GSZ + m) * 16 + (lane & 15);
                    af[m] = *reinterpret_cast<const f16x8*>(
                        ab + r * 64 + ((((lane >> 4)) ^ ((r >> 1) & 3)) << 4));
                }
                if (g == 0 && t + 1 < NT) stage_half(t + 1, kh);
                asm volatile("" ::: "memory");
                __builtin_amdgcn_s_barrier();
                asm volatile("s_waitcnt lgkmcnt(0)" ::: "memory");
                __builtin_amdgcn_sched_barrier(0);
                __builtin_amdgcn_s_setprio(1);
#pragma unroll
                for (int m = 0; m < GSZ; ++m)
#pragma unroll
                    for (int ni = 0; ni < NI; ++ni)
                        acc[g * GSZ + m][ni] = __builtin_amdgcn_mfma_f32_16x16x32_f16(
                            af[m], bf[ni], acc[g * GSZ + m][ni], 0, 0, 0);
                __builtin_amdgcn_s_setprio(0);
                if (g == NGROUP - 1) {
                    if (kh == 0) {
                        if (t == NT - 1) VMCNT_I(0);
                        else wait_n();
                    } else if (t + 1 < NT) {
                        wait_n();
                    }
                }
                asm volatile("" ::: "memory");
                __builtin_amdgcn_s_barrier();
                asm volatile("" ::: "memory");
            }
        }
    }

    if constexpr (FUSE_NR) {
        if (bcol >= V_OFF) {   // V tile -> transposed write (permuted cols)
#pragma unroll
            for (int mi = 0; mi < MI; ++mi)
#pragma unroll
                for (int ni = 0; ni < NI; ++ni) {
                    const int col = bcol - V_OFF + colOf(ni) + (lane & 15);
                    const int rb = brow + wm * (BM / WM) + mi * 16 + (lane >> 4) * 4;
#pragma unroll
                    for (int j = 0; j < 4; ++j)
                        vt[(size_t)col * M + rb + j] = (_Float16)acc[mi][ni][j];
                }
        } else {               // q/k tile -> fused RMSNorm + RoPE, in-register
            const bool is_q = (bcol < NH * HD);
            const float* nw = is_q ? qw : kw;
            const float sc = is_q ? SCALE : 1.0f;
            float* ssbuf = (float*)lds;          // [wm:2][head:2][row:96][wn:4]
            const int fidx = wn * 16 + (lane & 15);
            const float w0 = nw[fidx], w1 = nw[64 + fidx];
#pragma unroll
            for (int hl = 0; hl < 2; ++hl)
#pragma unroll
                for (int mi = 0; mi < MI; ++mi)
#pragma unroll
                    for (int j = 0; j < 4; ++j) {
                        float v0 = acc[mi][hl * 2 + 0][j];
                        float v1 = acc[mi][hl * 2 + 1][j];
                        float s = v0 * v0 + v1 * v1;
                        s += __shfl_xor(s, 1, 64);
                        s += __shfl_xor(s, 2, 64);
                        s += __shfl_xor(s, 4, 64);
                        s += __shfl_xor(s, 8, 64);
                        if ((lane & 15) == 0) {
                            const int rl = mi * 16 + (lane >> 4) * 4 + j;
                            ssbuf[(((wm * 2 + hl) * 96 + rl) << 2) + wn] = s;
                        }
                    }
            __syncthreads();
#pragma unroll
            for (int mi = 0; mi < MI; ++mi)
#pragma unroll
                for (int j = 0; j < 4; ++j) {
                    const int rl = mi * 16 + (lane >> 4) * 4 + j;
                    const int trow = brow + wm * (BM / WM) + rl;
                    float2 cssn = rope_tab[(size_t)trow * 64 + fidx];
#pragma unroll
                    for (int hl = 0; hl < 2; ++hl) {
                        float4 sv = *reinterpret_cast<const float4*>(
                            &ssbuf[((wm * 2 + hl) * 96 + rl) << 2]);
                        float rs = rsqrtf((sv.x + sv.y + sv.z + sv.w) * (1.0f / HD) + RMS_EPS);
                        float v0 = acc[mi][hl * 2 + 0][j] * rs * w0;
                        float v1 = acc[mi][hl * 2 + 1][j] * rs * w1;
                        float o0 = (v0 * cssn.x - v1 * cssn.y) * sc;
                        float o1 = (v1 * cssn.x + v0 * cssn.y) * sc;
                        const size_t base = (size_t)trow * N + bcol + hl * 128 + fidx;
                        C[base] = (OutT)o0;
                        C[base + 64] = (OutT)o1;
                    }
                }
        }
    } else if (SPLIT_V && bcol >= V_OFF) {
#pragma unroll
        for (int mi = 0; mi < MI; ++mi)
#pragma unroll
            for (int ni = 0; ni < NI; ++ni) {
                const int col = bcol - V_OFF + wn * (BN / WN) + ni * 16 + (lane & 15);
                const int rb = brow + wm * (BM / WM) + mi * 16 + (lane >> 4) * 4;
#pragma unroll
                for (int j = 0; j < 4; ++j)
                    vt[(size_t)col * M + rb + j] = (_Float16)acc[mi][ni][j];
            }
    } else {
#pragma unroll
        for (int mi = 0; mi < MI; ++mi)
#pragma unroll
            for (int ni = 0; ni < NI; ++ni) {
                const int col = bcol + wn * (BN / WN) + ni * 16 + (lane & 15);
                const int rb = brow + wm * (BM / WM) + mi * 16 + (lane >> 4) * 4;
#pragma unroll
                for (int j = 0; j < 4; ++j)
                    C[(size_t)(rb + j) * N + col] = (OutT)acc[mi][ni][j];
            }
    }
}

// ---------------------------------------------------------------------------
// prep: blocks [0,T_LEN): hs cast + gate=log_sigmoid(hs.g_w) + rope table.
//       blocks [T_LEN, T_LEN+6144): qkv_w / o_w f32->f16 cast.
// ---------------------------------------------------------------------------
__global__ __launch_bounds__(256) void prep_kernel(const float* __restrict__ hs,
                                                   const float* __restrict__ g_w,
                                                   const int* __restrict__ pos,
                                                   const float* __restrict__ qkv_w,
                                                   const float* __restrict__ o_w,
                                                   _Float16* __restrict__ hs16,
                                                   float* __restrict__ gate,
                                                   float2* __restrict__ rope_tab,
                                                   _Float16* __restrict__ qkvw16,
                                                   _Float16* __restrict__ ow16) {
    const int tid = threadIdx.x;
    if (blockIdx.x >= T_LEN) {   // weight cast branch
        constexpr int NA = QKV_COLS * HID_DIM;
        const int i = ((blockIdx.x - T_LEN) * 256 + tid) * 8;
        const float* src = (i < NA) ? qkv_w + i : o_w + (i - NA);
        _Float16* dst = (i < NA) ? qkvw16 + i : ow16 + (i - NA);
        float4 x = *reinterpret_cast<const float4*>(src);
        float4 y = *reinterpret_cast<const float4*>(src + 4);
        f16x8 o;
        o[0] = (_Float16)x.x; o[1] = (_Float16)x.y; o[2] = (_Float16)x.z; o[3] = (_Float16)x.w;
        o[4] = (_Float16)y.x; o[5] = (_Float16)y.y; o[6] = (_Float16)y.z; o[7] = (_Float16)y.w;
        *reinterpret_cast<f16x8*>(dst) = o;
        return;
    }
    const int t = blockIdx.x;
    const int lane = tid & 63, wave = tid >> 6;
    const int i = tid * 8;
    const float* row = hs + (size_t)t * HID_DIM;
    float4 a = *reinterpret_cast<const float4*>(&row[i]);
    float4 b = *reinterpret_cast<const float4*>(&row[i + 4]);
    f16x8 o;
    o[0] = (_Float16)a.x; o[1] = (_Float16)a.y; o[2] = (_Float16)a.z; o[3] = (_Float16)a.w;
    o[4] = (_Float16)b.x; o[5] = (_Float16)b.y; o[6] = (_Float16)b.z; o[7] = (_Float16)b.w;
    *reinterpret_cast<f16x8*>(&hs16[(size_t)t * HID_DIM + i]) = o;

    if (tid < 64) {
        float inv_freq = powf(THETA, -(float)tid * (1.0f / 64.0f));
        float ang = (float)pos[t] * inv_freq;
        float sn, cs;
        sincosf(ang, &sn, &cs);
        rope_tab[(size_t)t * 64 + tid] = make_float2(cs, sn);
    }

    float s[NKV];
#pragma unroll
    for (int h = 0; h < NKV; ++h) {
        const float4 wa = *reinterpret_cast<const float4*>(&g_w[(size_t)h * HID_DIM + i]);
        const float4 wb = *reinterpret_cast<const float4*>(&g_w[(size_t)h * HID_DIM + i + 4]);
        s[h] = a.x * wa.x + a.y * wa.y + a.z * wa.z + a.w * wa.w
             + b.x * wb.x + b.y * wb.y + b.z * wb.z + b.w * wb.w;
    }
#pragma unroll
    for (int off = 32; off > 0; off >>= 1)
#pragma unroll
        for (int h = 0; h < NKV; ++h) s[h] += __shfl_down(s[h], off, 64);
    __shared__ float red[4][NKV];
    if (lane == 0)
#pragma unroll
        for (int h = 0; h < NKV; ++h) red[wave][h] = s[h];
    __syncthreads();
    if (tid < NKV) {
        float x = red[0][tid] + red[1][tid] + red[2][tid] + red[3][tid];
        float ls = fminf(x, 0.f) - log1pf(expf(-fabsf(x)));
        gate[(size_t)t * NKV + tid] = ls;
    }
}

// ---------------------------------------------------------------------------
// Pipelined MFMA banded retention (r6 schedule). Consumes raw gate; builds
// the band-local prefix sum in LDS (decay uses cg DIFFERENCES only, so a
// local prefix over [s_lo, t0+64) is exactly equivalent to global cumsum).
// ---------------------------------------------------------------------------
__global__ __launch_bounds__(256, 2) void attn_mfma2(const _Float16* __restrict__ qkv,
                                                     const _Float16* __restrict__ vt,
                                                     const float* __restrict__ gate,
                                                     _Float16* __restrict__ out) {
    const int h = blockIdx.y;
    const int t0 = blockIdx.x * AQT;
    const int tid = threadIdx.x, lane = tid & 63, wid = tid >> 6;

    __shared__ char buf[4][16384];
    __shared__ char WsB[2][4096];
    __shared__ float cgS[BAND + AQT];

    const int s_lo = (t0 >= BAND) ? t0 - BAND : 0;
    const int NT = (t0 + AQT - s_lo) >> 5;
    const int span = t0 + AQT - s_lo;

    auto stage = [&](int t) {
        const int s0 = s_lo + t * 32;
        char* kd = (char*)buf + (size_t)(t & 3) * 16384;
        char* vd = kd + 8192;
#pragma unroll
        for (int i = 0; i < 2; ++i) {
            const int r = i * 16 + (tid >> 4);
            const int celem = (((tid & 15) * 16) ^ ((r & 7) << 4)) >> 1;
            gload_lds16(qkv + (size_t)(s0 + r) * QKV_COLS + NH * HD + h * HD + celem,
                        kd + i * 4096 + tid * 16);
        }
#pragma unroll
        for (int i = 0; i < 2; ++i) {
            const int d = i * 64 + (tid >> 2);
            const int key = (d ^ (d >> 2)) & 3;
            gload_lds16(vt + (size_t)(h * HD + d) * T_LEN + s0 + 8 * ((tid & 3) ^ key),
                        vd + i * 4096 + tid * 16);
        }
    };

    stage(0); stage(1); stage(2);   // issue vmem early; scan overlaps latency

    // load gate slice and build local inclusive prefix in cgS
    if (tid < span) cgS[tid] = gate[(size_t)(s_lo + tid) * NKV + h];
    if (256 + tid < span) cgS[256 + tid] = gate[(size_t)(s_lo + 256 + tid) * NKV + h];
    __syncthreads();
    // Hillis-Steele over [0, min(span,256))
    for (int off = 1; off < 256; off <<= 1) {
        float add = (tid >= off && tid < span) ? cgS[tid - off] : 0.f;
        __syncthreads();
        if (tid >= off && tid < span) cgS[tid] += add;
        __syncthreads();
    }
    if (span > 256) {   // tail [256, span): scan within tail, then add base
        const int ti = 256 + tid;
        for (int off = 1; off < 64; off <<= 1) {
            float add = (tid >= off && ti < span) ? cgS[ti - off] : 0.f;
            __syncthreads();
            if (tid >= off && ti < span) cgS[ti] += add;
            __syncthreads();
        }
        float base = cgS[255];
        __syncthreads();
        if (ti < span) cgS[ti] += base;
    }

    f16x8 qa[2][4];
    {
        const int qrow = t0 + wid * 16 + (lane & 15);
#pragma unroll
        for (int hh = 0; hh < 2; ++hh) {
            const _Float16* qp = qkv + (size_t)qrow * QKV_COLS + (2 * h + hh) * HD + (lane >> 4) * 8;
#pragma unroll
            for (int kq = 0; kq < 4; ++kq)
                qa[hh][kq] = *reinterpret_cast<const f16x8*>(qp + kq * 32);
        }
    }
    __syncthreads();   // drains staging vmem + scan writes

    float cqr[4];
#pragma unroll
    for (int j = 0; j < 4; ++j)
        cqr[j] = cgS[(span - AQT) + wid * 16 + (lane >> 4) * 4 + j];

    f32x4 acc_o[2][8];
#pragma unroll
    for (int hh = 0; hh < 2; ++hh)
#pragma unroll
        for (int nq = 0; nq < 8; ++nq) acc_o[hh][nq] = (f32x4){0.f, 0.f, 0.f, 0.f};
    float dsum[2][4] = {{0.f, 0.f, 0.f, 0.f}, {0.f, 0.f, 0.f, 0.f}};

    for (int t = 0; t < NT; ++t) {
        if (t + 3 < NT) stage(t + 3);
        const char* kbase = (const char*)buf + (size_t)(t & 3) * 16384;
        const char* vbase = kbase + 8192;
        const int s0 = s_lo + t * 32;

        f16x8 kf[2][4];
#pragma unroll
        for (int c = 0; c < 2; ++c) {
            const int rr = c * 16 + (lane & 15);
#pragma unroll
            for (int kq = 0; kq < 4; ++kq) {
                const int bi = (kq * 64 + (lane >> 4) * 16) ^ ((rr & 7) << 4);
                kf[c][kq] = *reinterpret_cast<const f16x8*>(kbase + rr * 256 + bi);
            }
        }
        float csv[2];
        csv[0] = cgS[t * 32 + (lane & 15)];
        csv[1] = cgS[t * 32 + 16 + (lane & 15)];

#pragma unroll
        for (int hh = 0; hh < 2; ++hh) {
            f32x4 accs[2];
            accs[0] = (f32x4){0.f, 0.f, 0.f, 0.f};
            accs[1] = (f32x4){0.f, 0.f, 0.f, 0.f};
#pragma unroll
            for (int c = 0; c < 2; ++c)
#pragma unroll
                for (int kq = 0; kq < 4; ++kq)
                    accs[c] = __builtin_amdgcn_mfma_f32_16x16x32_f16(
                        qa[hh][kq], kf[c][kq], accs[c], 0, 0, 0);
#pragma unroll
            for (int c = 0; c < 2; ++c) {
                const int sg = s0 + c * 16 + (lane & 15);
#pragma unroll
                for (int j = 0; j < 4; ++j) {
                    const int qg = t0 + wid * 16 + (lane >> 4) * 4 + j;
                    const float sv = accs[c][j];
                    const float w = (sg <= qg) ? __expf(cqr[j] - csv[c]) * sv * sv : 0.f;
                    const _Float16 wh = (_Float16)w;
                    dsum[hh][j] += (float)wh;
                    const int q = wid * 16 + (lane >> 4) * 4 + j;
                    const int addr = q * 64 +
                        ((2 * (c * 16 + (lane & 15))) ^ (((q ^ (q >> 2)) & 3) << 4));
                    *(_Float16*)(WsB[hh] + addr) = wh;
                }
            }
        }
        asm volatile("s_waitcnt lgkmcnt(0)" ::: "memory");
        __builtin_amdgcn_sched_barrier(0);

        const int qr = wid * 16 + (lane & 15);
        const int wb = qr * 64 + (((lane >> 4) * 16) ^ (((qr ^ (qr >> 2)) & 3) << 4));
        f16x8 wf0 = *reinterpret_cast<const f16x8*>(WsB[0] + wb);
        f16x8 wf1 = *reinterpret_cast<const f16x8*>(WsB[1] + wb);
        f16x8 vf[8];
#pragma unroll
        for (int nq = 0; nq < 8; ++nq) {
            const int dr = nq * 16 + (lane & 15);
            const int vb = dr * 64 + (((lane >> 4) * 16) ^ (((dr ^ (dr >> 2)) & 3) << 4));
            vf[nq] = *reinterpret_cast<const f16x8*>(vbase + vb);
        }
        __builtin_amdgcn_s_setprio(1);
#pragma unroll
        for (int nq = 0; nq < 8; ++nq) {
            acc_o[0][nq] = __builtin_amdgcn_mfma_f32_16x16x32_f16(wf0, vf[nq], acc_o[0][nq], 0, 0, 0);
            acc_o[1][nq] = __builtin_amdgcn_mfma_f32_16x16x32_f16(wf1, vf[nq], acc_o[1][nq], 0, 0, 0);
        }
        __builtin_amdgcn_s_setprio(0);

        const int rem = NT - 1 - t;
        if (rem >= 3)      asm volatile("s_waitcnt vmcnt(8)" ::: "memory");
        else if (rem == 2) asm volatile("s_waitcnt vmcnt(4)" ::: "memory");
        else if (rem == 1) asm volatile("s_waitcnt vmcnt(0)" ::: "memory");
        asm volatile("" ::: "memory");
        if (rem > 0) __builtin_amdgcn_s_barrier();
        asm volatile("" ::: "memory");
    }

#pragma unroll
    for (int hh = 0; hh < 2; ++hh) {
        float inv[4];
#pragma unroll
        for (int j = 0; j < 4; ++j) {
            float d = dsum[hh][j];
            d += __shfl_xor(d, 1, 64);
            d += __shfl_xor(d, 2, 64);
            d += __shfl_xor(d, 4, 64);
            d += __shfl_xor(d, 8, 64);
            inv[j] = 1.f / (d + NORM_EPS);
        }
#pragma unroll
        for (int nq = 0; nq < 8; ++nq)
#pragma unroll
            for (int j = 0; j < 4; ++j) {
                const int row = t0 + wid * 16 + (lane >> 4) * 4 + j;
                out[(size_t)row * (NH * HD) + (2 * h + hh) * HD + nq * 16 + (lane & 15)] =
                    (_Float16)(acc_o[hh][nq][j] * inv[j]);
            }
    }
}

// ---------------------------------------------------------------------------
extern "C" void kernel_launch(void* const* d_in, const int* in_sizes, int n_in,
                              void* d_out, int out_size, void* d_ws, size_t ws_size,
                              hipStream_t stream) {
    const float* hs    = (const float*)d_in[0];
    const float* qkv_w = (const float*)d_in[1];
    const float* g_w   = (const float*)d_in[2];
    const float* o_w   = (const float*)d_in[3];
    const float* q_nw  = (const float*)d_in[4];
    const float* k_nw  = (const float*)d_in[5];
    const int*   pos   = (const int*)d_in[6];

    _Float16* hs16   = (_Float16*)d_ws;                      // 3072*2048 (reused for attn out)
    _Float16* qkvw16 = hs16 + (size_t)T_LEN * HID_DIM;       // 4096*2048
    _Float16* ow16   = qkvw16 + (size_t)QKV_COLS * HID_DIM;  // 2048*2048
    _Float16* qkv16  = ow16 + (size_t)HID_DIM * HID_DIM;     // 3072*4096 (v region unused)
    _Float16* vtb    = qkv16 + (size_t)T_LEN * QKV_COLS;     // 1024*3072 (V transposed)
    float* gate = (float*)(vtb + (size_t)NKV * HD * T_LEN);
    float2* rope_tab = (float2*)(gate + (size_t)T_LEN * NKV);  // 3072*64*8B

    constexpr int NW = (QKV_COLS * HID_DIM + HID_DIM * HID_DIM) / 2048;  // 6144
    // 1. prep: hs cast + gate + rope table + weight casts (one launch)
    prep_kernel<<<T_LEN + NW, 256, 0, stream>>>(hs, g_w, pos, qkv_w, o_w,
                                                hs16, gate, rope_tab, qkvw16, ow16);
    // 2. qkv projection: 192x256 tiles, 256 blocks; RMSNorm+RoPE fused
    gemm_mph<T_LEN, QKV_COLS, HID_DIM, 192, 256, 2, 4, 2, _Float16, true, true>
        <<<(T_LEN / 192) * (QKV_COLS / 256), 512, 0, stream>>>(
            hs16, qkvw16, qkv16, vtb, q_nw, k_nw, rope_tab);
    // 3. pipelined retention (band-local gate prefix in-block): 48 x 8 blocks
    attn_mfma2<<<dim3(T_LEN / AQT, NKV), 256, 0, stream>>>(qkv16, vtb, gate, hs16);
    // 4. output projection: 192x128 tiles, 256 blocks (2 blocks/CU)
    gemm_mph<T_LEN, HID_DIM, HID_DIM, 192, 128, 4, 2, 4, float, false, false>
        <<<(T_LEN / 192) * (HID_DIM / 128), 512, 0, stream>>>(
            hs16, ow16, (float*)d_out, nullptr, nullptr, nullptr, nullptr);
    (void)in_sizes; (void)n_in; (void)out_size; (void)ws_size;
}

// Round 14
// 148.719 us; speedup vs baseline: 1.4688x; 1.0485x over previous
//
#include <hip/hip_runtime.h>
#include <math.h>

#define T_LEN 3072
#define HID_DIM 2048
#define NH 16
#define NKV 8
#define HD 128
#define QKV_COLS ((NH + 2 * NKV) * HD)   // 4096
#define V_OFF (NH * HD + NKV * HD)       // 3072
#define RMS_EPS 1e-6f
#define NORM_EPS 1e-6f
#define THETA 10000.0f
#define SCALE 0.08838834764831845f       // 128^-0.5

#define BAND 256   // exp(-0.65*256)=e^-167 -> exactly 0 in f32; validated round 1
#define AQT 64     // q rows per attn block
#define ATTN_BLKS ((T_LEN / AQT) * NKV)  // 384
#define OW_RIDERS ((HID_DIM * HID_DIM) / 2048)  // 2048

typedef __attribute__((ext_vector_type(8))) _Float16 f16x8;
typedef __attribute__((ext_vector_type(4))) float f32x4;

__device__ __forceinline__ void gload_lds16(const void* g, void* l) {
    __builtin_amdgcn_global_load_lds((const __attribute__((address_space(1))) void*)g,
                                     (__attribute__((address_space(3))) void*)l, 16, 0, 0);
}
__device__ __forceinline__ void gload_lds4(const void* g, void* l) {
    __builtin_amdgcn_global_load_lds((const __attribute__((address_space(1))) void*)g,
                                     (__attribute__((address_space(3))) void*)l, 4, 0, 0);
}

#define VMCNT_I(n) asm volatile("s_waitcnt vmcnt(" #n ")" ::: "memory")

// ---------------------------------------------------------------------------
// m201-granularity f16 MFMA GEMM (r9-r13 schedule, 0 conflicts).
// r13 change: pre-MFMA barrier removed (1 barrier/phase). Staging writes hit
// buffer (t+1)&1 while reads hit t&1 (disjoint); own-wave read->MFMA order is
// lgkmcnt(0)+sched_barrier; the vmcnt-guarded post-barrier still fences both
// the half-landing and cross-K-tile buffer reuse.
// FUSE_NR (qkv): permuted column map -> rope pair in-register (r12, verified).
// ---------------------------------------------------------------------------
template <int M, int N, int K, int BM, int BN, int WM, int WN, int WPE,
          typename OutT, bool SPLIT_V, bool FUSE_NR>
__global__ __launch_bounds__(512, WPE) void gemm_mph(const _Float16* __restrict__ A,
                                                     const _Float16* __restrict__ Bp,
                                                     OutT* __restrict__ C,
                                                     _Float16* __restrict__ vt,
                                                     const float* __restrict__ qw,
                                                     const float* __restrict__ kw,
                                                     const float2* __restrict__ rope_tab) {
    constexpr int MI = BM / WM / 16;
    constexpr int NGROUP = (MI >= 6) ? 2 : 1;
    constexpr int GSZ = MI / NGROUP;
    constexpr int NI = BN / WN / 16;
    constexpr int NT = K / 64;
    constexpr int NX = N / BN;
    constexpr int HALF = (BM + BN) * 64;
    constexpr int FULL = HALF / 8192;
    constexpr int REM = HALF - FULL * 8192;
    constexpr int NISS = FULL + (REM ? 2 : 0);
    static_assert(REM == 0 || REM == 4096, "staging remainder must be 4KB");
    static_assert(!FUSE_NR || (BN == 256 && WN == 4), "FUSE_NR needs BN=256, WN=4");
    __shared__ char lds[2 * 2 * HALF];

    const int tid = threadIdx.x, lane = tid & 63, wid = tid >> 6;
    const int wm = wid / WN, wn = wid % WN;
    const int q8 = gridDim.x >> 3;
    const int sw = (blockIdx.x & 7) * q8 + (blockIdx.x >> 3);
    const int brow = (sw / NX) * BM, bcol = (sw % NX) * BN;

    auto colOf = [&](int ni) {
        if constexpr (FUSE_NR) return (ni >> 1) * 128 + (ni & 1) * 64 + wn * 16;
        else                   return wn * (BN / WN) + ni * 16;
    };

    auto stage_half = [&](int t, int kh) {
        char* hb = lds + (size_t)((t & 1) * 2 + kh) * HALF;
        const int k0 = t * 64 + kh * 32;
#pragma unroll
        for (int j = 0; j < FULL; ++j) {
            const int L = j * 8192 + tid * 16;
            if (L < BM * 64) {
                const int r = L >> 6;
                const int c = ((L >> 4) & 3) ^ ((r >> 1) & 3);
                gload_lds16(A + (size_t)(brow + r) * K + k0 + c * 8, hb + L);
            } else {
                const int Lb = L - BM * 64;
                const int r = Lb >> 6;
                const int c = ((Lb >> 4) & 3) ^ ((r >> 1) & 3);
                gload_lds16(Bp + (size_t)(bcol + r) * K + k0 + c * 8, hb + L);
            }
        }
        if constexpr (REM != 0) {
#pragma unroll
            for (int j = 0; j < 2; ++j) {
                const int L = FULL * 8192 + j * 2048 + (tid >> 6) * 256 + (tid & 63) * 4;
                const int Lb = L - BM * 64;
                const int r = Lb >> 6;
                const int wb = Lb & 63;
                const int c = (wb >> 4) ^ ((r >> 1) & 3);
                gload_lds4(Bp + (size_t)(bcol + r) * K + k0 + c * 8 + ((wb & 15) >> 1),
                           hb + (L & ~255));
            }
        }
    };
    auto wait_n = [&]() {
        if constexpr (NISS == 5) VMCNT_I(5);
        else if constexpr (NISS == 4) VMCNT_I(4);
        else VMCNT_I(3);
    };

    f32x4 acc[MI][NI];
#pragma unroll
    for (int mi = 0; mi < MI; ++mi)
#pragma unroll
        for (int ni = 0; ni < NI; ++ni) acc[mi][ni] = (f32x4){0.f, 0.f, 0.f, 0.f};

    stage_half(0, 0);
    stage_half(0, 1);
    wait_n();
    asm volatile("" ::: "memory");
    __builtin_amdgcn_s_barrier();
    asm volatile("" ::: "memory");

    for (int t = 0; t < NT; ++t) {
        const char* buf = lds + (size_t)(t & 1) * 2 * HALF;
#pragma unroll
        for (int kh = 0; kh < 2; ++kh) {
            const char* ab = buf + kh * HALF;
            const char* bb = ab + BM * 64;
            f16x8 bf[NI];
#pragma unroll
            for (int g = 0; g < NGROUP; ++g) {
                if (g == 0) {
#pragma unroll
                    for (int ni = 0; ni < NI; ++ni) {
                        const int r = colOf(ni) + (lane & 15);
                        bf[ni] = *reinterpret_cast<const f16x8*>(
                            bb + r * 64 + ((((lane >> 4)) ^ ((r >> 1) & 3)) << 4));
                    }
                }
                f16x8 af[GSZ];
#pragma unroll
                for (int m = 0; m < GSZ; ++m) {
                    const int r = wm * (BM / WM) + (g * GSZ + m) * 16 + (lane & 15);
                    af[m] = *reinterpret_cast<const f16x8*>(
                        ab + r * 64 + ((((lane >> 4)) ^ ((r >> 1) & 3)) << 4));
                }
                if (g == 0 && t + 1 < NT) stage_half(t + 1, kh);
                asm volatile("s_waitcnt lgkmcnt(0)" ::: "memory");
                __builtin_amdgcn_sched_barrier(0);
                __builtin_amdgcn_s_setprio(1);
#pragma unroll
                for (int m = 0; m < GSZ; ++m)
#pragma unroll
                    for (int ni = 0; ni < NI; ++ni)
                        acc[g * GSZ + m][ni] = __builtin_amdgcn_mfma_f32_16x16x32_f16(
                            af[m], bf[ni], acc[g * GSZ + m][ni], 0, 0, 0);
                __builtin_amdgcn_s_setprio(0);
                if (g == NGROUP - 1) {
                    if (kh == 0) {
                        if (t == NT - 1) VMCNT_I(0);
                        else wait_n();
                    } else if (t + 1 < NT) {
                        wait_n();
                    }
                }
                asm volatile("" ::: "memory");
                __builtin_amdgcn_s_barrier();
                asm volatile("" ::: "memory");
            }
        }
    }

    if constexpr (FUSE_NR) {
        if (bcol >= V_OFF) {   // V tile -> transposed write (permuted cols)
#pragma unroll
            for (int mi = 0; mi < MI; ++mi)
#pragma unroll
                for (int ni = 0; ni < NI; ++ni) {
                    const int col = bcol - V_OFF + colOf(ni) + (lane & 15);
                    const int rb = brow + wm * (BM / WM) + mi * 16 + (lane >> 4) * 4;
#pragma unroll
                    for (int j = 0; j < 4; ++j)
                        vt[(size_t)col * M + rb + j] = (_Float16)acc[mi][ni][j];
                }
        } else {               // q/k tile -> fused RMSNorm + RoPE, in-register
            const bool is_q = (bcol < NH * HD);
            const float* nw = is_q ? qw : kw;
            const float sc = is_q ? SCALE : 1.0f;
            float* ssbuf = (float*)lds;          // [wm:2][head:2][row:96][wn:4]
            const int fidx = wn * 16 + (lane & 15);
            const float w0 = nw[fidx], w1 = nw[64 + fidx];
#pragma unroll
            for (int hl = 0; hl < 2; ++hl)
#pragma unroll
                for (int mi = 0; mi < MI; ++mi)
#pragma unroll
                    for (int j = 0; j < 4; ++j) {
                        float v0 = acc[mi][hl * 2 + 0][j];
                        float v1 = acc[mi][hl * 2 + 1][j];
                        float s = v0 * v0 + v1 * v1;
                        s += __shfl_xor(s, 1, 64);
                        s += __shfl_xor(s, 2, 64);
                        s += __shfl_xor(s, 4, 64);
                        s += __shfl_xor(s, 8, 64);
                        if ((lane & 15) == 0) {
                            const int rl = mi * 16 + (lane >> 4) * 4 + j;
                            ssbuf[(((wm * 2 + hl) * 96 + rl) << 2) + wn] = s;
                        }
                    }
            __syncthreads();
#pragma unroll
            for (int mi = 0; mi < MI; ++mi)
#pragma unroll
                for (int j = 0; j < 4; ++j) {
                    const int rl = mi * 16 + (lane >> 4) * 4 + j;
                    const int trow = brow + wm * (BM / WM) + rl;
                    float2 cssn = rope_tab[(size_t)trow * 64 + fidx];
#pragma unroll
                    for (int hl = 0; hl < 2; ++hl) {
                        float4 sv = *reinterpret_cast<const float4*>(
                            &ssbuf[((wm * 2 + hl) * 96 + rl) << 2]);
                        float rs = rsqrtf((sv.x + sv.y + sv.z + sv.w) * (1.0f / HD) + RMS_EPS);
                        float v0 = acc[mi][hl * 2 + 0][j] * rs * w0;
                        float v1 = acc[mi][hl * 2 + 1][j] * rs * w1;
                        float o0 = (v0 * cssn.x - v1 * cssn.y) * sc;
                        float o1 = (v1 * cssn.x + v0 * cssn.y) * sc;
                        const size_t base = (size_t)trow * N + bcol + hl * 128 + fidx;
                        C[base] = (OutT)o0;
                        C[base + 64] = (OutT)o1;
                    }
                }
        }
    } else if (SPLIT_V && bcol >= V_OFF) {
#pragma unroll
        for (int mi = 0; mi < MI; ++mi)
#pragma unroll
            for (int ni = 0; ni < NI; ++ni) {
                const int col = bcol - V_OFF + wn * (BN / WN) + ni * 16 + (lane & 15);
                const int rb = brow + wm * (BM / WM) + mi * 16 + (lane >> 4) * 4;
#pragma unroll
                for (int j = 0; j < 4; ++j)
                    vt[(size_t)col * M + rb + j] = (_Float16)acc[mi][ni][j];
            }
    } else {
#pragma unroll
        for (int mi = 0; mi < MI; ++mi)
#pragma unroll
            for (int ni = 0; ni < NI; ++ni) {
                const int col = bcol + wn * (BN / WN) + ni * 16 + (lane & 15);
                const int rb = brow + wm * (BM / WM) + mi * 16 + (lane >> 4) * 4;
#pragma unroll
                for (int j = 0; j < 4; ++j)
                    C[(size_t)(rb + j) * N + col] = (OutT)acc[mi][ni][j];
            }
    }
}

// ---------------------------------------------------------------------------
// prep: blocks [0,T_LEN): hs cast + gate=log_sigmoid(hs.g_w) + rope table.
//       blocks [T_LEN, T_LEN+4096): qkv_w f32->f16 cast. (o_w cast moved to
//       rider blocks in the attn launch — not needed until the o-proj.)
// ---------------------------------------------------------------------------
__global__ __launch_bounds__(256) void prep_kernel(const float* __restrict__ hs,
                                                   const float* __restrict__ g_w,
                                                   const int* __restrict__ pos,
                                                   const float* __restrict__ qkv_w,
                                                   _Float16* __restrict__ hs16,
                                                   float* __restrict__ gate,
                                                   float2* __restrict__ rope_tab,
                                                   _Float16* __restrict__ qkvw16) {
    const int tid = threadIdx.x;
    if (blockIdx.x >= T_LEN) {   // qkv weight cast branch
        const int i = ((blockIdx.x - T_LEN) * 256 + tid) * 8;
        float4 x = *reinterpret_cast<const float4*>(qkv_w + i);
        float4 y = *reinterpret_cast<const float4*>(qkv_w + i + 4);
        f16x8 o;
        o[0] = (_Float16)x.x; o[1] = (_Float16)x.y; o[2] = (_Float16)x.z; o[3] = (_Float16)x.w;
        o[4] = (_Float16)y.x; o[5] = (_Float16)y.y; o[6] = (_Float16)y.z; o[7] = (_Float16)y.w;
        *reinterpret_cast<f16x8*>(qkvw16 + i) = o;
        return;
    }
    const int t = blockIdx.x;
    const int lane = tid & 63, wave = tid >> 6;
    const int i = tid * 8;
    const float* row = hs + (size_t)t * HID_DIM;
    float4 a = *reinterpret_cast<const float4*>(&row[i]);
    float4 b = *reinterpret_cast<const float4*>(&row[i + 4]);
    f16x8 o;
    o[0] = (_Float16)a.x; o[1] = (_Float16)a.y; o[2] = (_Float16)a.z; o[3] = (_Float16)a.w;
    o[4] = (_Float16)b.x; o[5] = (_Float16)b.y; o[6] = (_Float16)b.z; o[7] = (_Float16)b.w;
    *reinterpret_cast<f16x8*>(&hs16[(size_t)t * HID_DIM + i]) = o;

    if (tid < 64) {
        float inv_freq = powf(THETA, -(float)tid * (1.0f / 64.0f));
        float ang = (float)pos[t] * inv_freq;
        float sn, cs;
        sincosf(ang, &sn, &cs);
        rope_tab[(size_t)t * 64 + tid] = make_float2(cs, sn);
    }

    float s[NKV];
#pragma unroll
    for (int h = 0; h < NKV; ++h) {
        const float4 wa = *reinterpret_cast<const float4*>(&g_w[(size_t)h * HID_DIM + i]);
        const float4 wb = *reinterpret_cast<const float4*>(&g_w[(size_t)h * HID_DIM + i + 4]);
        s[h] = a.x * wa.x + a.y * wa.y + a.z * wa.z + a.w * wa.w
             + b.x * wb.x + b.y * wb.y + b.z * wb.z + b.w * wb.w;
    }
#pragma unroll
    for (int off = 32; off > 0; off >>= 1)
#pragma unroll
        for (int h = 0; h < NKV; ++h) s[h] += __shfl_down(s[h], off, 64);
    __shared__ float red[4][NKV];
    if (lane == 0)
#pragma unroll
        for (int h = 0; h < NKV; ++h) red[wave][h] = s[h];
    __syncthreads();
    if (tid < NKV) {
        float x = red[0][tid] + red[1][tid] + red[2][tid] + red[3][tid];
        float ls = fminf(x, 0.f) - log1pf(expf(-fabsf(x)));
        gate[(size_t)t * NKV + tid] = ls;
    }
}

// ---------------------------------------------------------------------------
// Pipelined MFMA banded retention (r6 schedule, r12 in-block gate scan).
// Flattened 1D grid: blocks [0, 384) = attn (h = b&7, tq = b>>3);
// blocks [384, 384+2048) = o_w f32->f16 cast riders (stream under the
// latency-bound attn blocks; o_w needed only by the subsequent o-proj).
// ---------------------------------------------------------------------------
__global__ __launch_bounds__(256, 2) void attn_mfma2(const _Float16* __restrict__ qkv,
                                                     const _Float16* __restrict__ vt,
                                                     const float* __restrict__ gate,
                                                     _Float16* __restrict__ out,
                                                     const float* __restrict__ o_w,
                                                     _Float16* __restrict__ ow16) {
    const int tid = threadIdx.x;
    if (blockIdx.x >= ATTN_BLKS) {   // o_w cast rider
        const int i = ((blockIdx.x - ATTN_BLKS) * 256 + tid) * 8;
        float4 x = *reinterpret_cast<const float4*>(o_w + i);
        float4 y = *reinterpret_cast<const float4*>(o_w + i + 4);
        f16x8 o;
        o[0] = (_Float16)x.x; o[1] = (_Float16)x.y; o[2] = (_Float16)x.z; o[3] = (_Float16)x.w;
        o[4] = (_Float16)y.x; o[5] = (_Float16)y.y; o[6] = (_Float16)y.z; o[7] = (_Float16)y.w;
        *reinterpret_cast<f16x8*>(ow16 + i) = o;
        return;
    }
    const int h = blockIdx.x & 7;
    const int t0 = (blockIdx.x >> 3) * AQT;
    const int lane = tid & 63, wid = tid >> 6;

    __shared__ char buf[4][16384];
    __shared__ char WsB[2][4096];
    __shared__ float cgS[BAND + AQT];

    const int s_lo = (t0 >= BAND) ? t0 - BAND : 0;
    const int NT = (t0 + AQT - s_lo) >> 5;
    const int span = t0 + AQT - s_lo;

    auto stage = [&](int t) {
        const int s0 = s_lo + t * 32;
        char* kd = (char*)buf + (size_t)(t & 3) * 16384;
        char* vd = kd + 8192;
#pragma unroll
        for (int i = 0; i < 2; ++i) {
            const int r = i * 16 + (tid >> 4);
            const int celem = (((tid & 15) * 16) ^ ((r & 7) << 4)) >> 1;
            gload_lds16(qkv + (size_t)(s0 + r) * QKV_COLS + NH * HD + h * HD + celem,
                        kd + i * 4096 + tid * 16);
        }
#pragma unroll
        for (int i = 0; i < 2; ++i) {
            const int d = i * 64 + (tid >> 2);
            const int key = (d ^ (d >> 2)) & 3;
            gload_lds16(vt + (size_t)(h * HD + d) * T_LEN + s0 + 8 * ((tid & 3) ^ key),
                        vd + i * 4096 + tid * 16);
        }
    };

    stage(0); stage(1); stage(2);   // issue vmem early; scan overlaps latency

    if (tid < span) cgS[tid] = gate[(size_t)(s_lo + tid) * NKV + h];
    if (256 + tid < span) cgS[256 + tid] = gate[(size_t)(s_lo + 256 + tid) * NKV + h];
    __syncthreads();
    for (int off = 1; off < 256; off <<= 1) {
        float add = (tid >= off && tid < span) ? cgS[tid - off] : 0.f;
        __syncthreads();
        if (tid >= off && tid < span) cgS[tid] += add;
        __syncthreads();
    }
    if (span > 256) {
        const int ti = 256 + tid;
        for (int off = 1; off < 64; off <<= 1) {
            float add = (tid >= off && ti < span) ? cgS[ti - off] : 0.f;
            __syncthreads();
            if (tid >= off && ti < span) cgS[ti] += add;
            __syncthreads();
        }
        float base = cgS[255];
        __syncthreads();
        if (ti < span) cgS[ti] += base;
    }

    f16x8 qa[2][4];
    {
        const int qrow = t0 + wid * 16 + (lane & 15);
#pragma unroll
        for (int hh = 0; hh < 2; ++hh) {
            const _Float16* qp = qkv + (size_t)qrow * QKV_COLS + (2 * h + hh) * HD + (lane >> 4) * 8;
#pragma unroll
            for (int kq = 0; kq < 4; ++kq)
                qa[hh][kq] = *reinterpret_cast<const f16x8*>(qp + kq * 32);
        }
    }
    __syncthreads();

    float cqr[4];
#pragma unroll
    for (int j = 0; j < 4; ++j)
        cqr[j] = cgS[(span - AQT) + wid * 16 + (lane >> 4) * 4 + j];

    f32x4 acc_o[2][8];
#pragma unroll
    for (int hh = 0; hh < 2; ++hh)
#pragma unroll
        for (int nq = 0; nq < 8; ++nq) acc_o[hh][nq] = (f32x4){0.f, 0.f, 0.f, 0.f};
    float dsum[2][4] = {{0.f, 0.f, 0.f, 0.f}, {0.f, 0.f, 0.f, 0.f}};

    for (int t = 0; t < NT; ++t) {
        if (t + 3 < NT) stage(t + 3);
        const char* kbase = (const char*)buf + (size_t)(t & 3) * 16384;
        const char* vbase = kbase + 8192;
        const int s0 = s_lo + t * 32;

        f16x8 kf[2][4];
#pragma unroll
        for (int c = 0; c < 2; ++c) {
            const int rr = c * 16 + (lane & 15);
#pragma unroll
            for (int kq = 0; kq < 4; ++kq) {
                const int bi = (kq * 64 + (lane >> 4) * 16) ^ ((rr & 7) << 4);
                kf[c][kq] = *reinterpret_cast<const f16x8*>(kbase + rr * 256 + bi);
            }
        }
        float csv[2];
        csv[0] = cgS[t * 32 + (lane & 15)];
        csv[1] = cgS[t * 32 + 16 + (lane & 15)];

#pragma unroll
        for (int hh = 0; hh < 2; ++hh) {
            f32x4 accs[2];
            accs[0] = (f32x4){0.f, 0.f, 0.f, 0.f};
            accs[1] = (f32x4){0.f, 0.f, 0.f, 0.f};
#pragma unroll
            for (int c = 0; c < 2; ++c)
#pragma unroll
                for (int kq = 0; kq < 4; ++kq)
                    accs[c] = __builtin_amdgcn_mfma_f32_16x16x32_f16(
                        qa[hh][kq], kf[c][kq], accs[c], 0, 0, 0);
#pragma unroll
            for (int c = 0; c < 2; ++c) {
                const int sg = s0 + c * 16 + (lane & 15);
#pragma unroll
                for (int j = 0; j < 4; ++j) {
                    const int qg = t0 + wid * 16 + (lane >> 4) * 4 + j;
                    const float sv = accs[c][j];
                    const float w = (sg <= qg) ? __expf(cqr[j] - csv[c]) * sv * sv : 0.f;
                    const _Float16 wh = (_Float16)w;
                    dsum[hh][j] += (float)wh;
                    const int q = wid * 16 + (lane >> 4) * 4 + j;
                    const int addr = q * 64 +
                        ((2 * (c * 16 + (lane & 15))) ^ (((q ^ (q >> 2)) & 3) << 4));
                    *(_Float16*)(WsB[hh] + addr) = wh;
                }
            }
        }
        asm volatile("s_waitcnt lgkmcnt(0)" ::: "memory");
        __builtin_amdgcn_sched_barrier(0);

        const int qr = wid * 16 + (lane & 15);
        const int wb = qr * 64 + (((lane >> 4) * 16) ^ (((qr ^ (qr >> 2)) & 3) << 4));
        f16x8 wf0 = *reinterpret_cast<const f16x8*>(WsB[0] + wb);
        f16x8 wf1 = *reinterpret_cast<const f16x8*>(WsB[1] + wb);
        f16x8 vf[8];
#pragma unroll
        for (int nq = 0; nq < 8; ++nq) {
            const int dr = nq * 16 + (lane & 15);
            const int vb = dr * 64 + (((lane >> 4) * 16) ^ (((dr ^ (dr >> 2)) & 3) << 4));
            vf[nq] = *reinterpret_cast<const f16x8*>(vbase + vb);
        }
        __builtin_amdgcn_s_setprio(1);
#pragma unroll
        for (int nq = 0; nq < 8; ++nq) {
            acc_o[0][nq] = __builtin_amdgcn_mfma_f32_16x16x32_f16(wf0, vf[nq], acc_o[0][nq], 0, 0, 0);
            acc_o[1][nq] = __builtin_amdgcn_mfma_f32_16x16x32_f16(wf1, vf[nq], acc_o[1][nq], 0, 0, 0);
        }
        __builtin_amdgcn_s_setprio(0);

        const int rem = NT - 1 - t;
        if (rem >= 3)      asm volatile("s_waitcnt vmcnt(8)" ::: "memory");
        else if (rem == 2) asm volatile("s_waitcnt vmcnt(4)" ::: "memory");
        else if (rem == 1) asm volatile("s_waitcnt vmcnt(0)" ::: "memory");
        asm volatile("" ::: "memory");
        if (rem > 0) __builtin_amdgcn_s_barrier();
        asm volatile("" ::: "memory");
    }

#pragma unroll
    for (int hh = 0; hh < 2; ++hh) {
        float inv[4];
#pragma unroll
        for (int j = 0; j < 4; ++j) {
            float d = dsum[hh][j];
            d += __shfl_xor(d, 1, 64);
            d += __shfl_xor(d, 2, 64);
            d += __shfl_xor(d, 4, 64);
            d += __shfl_xor(d, 8, 64);
            inv[j] = 1.f / (d + NORM_EPS);
        }
#pragma unroll
        for (int nq = 0; nq < 8; ++nq)
#pragma unroll
            for (int j = 0; j < 4; ++j) {
                const int row = t0 + wid * 16 + (lane >> 4) * 4 + j;
                out[(size_t)row * (NH * HD) + (2 * h + hh) * HD + nq * 16 + (lane & 15)] =
                    (_Float16)(acc_o[hh][nq][j] * inv[j]);
            }
    }
}

// ---------------------------------------------------------------------------
extern "C" void kernel_launch(void* const* d_in, const int* in_sizes, int n_in,
                              void* d_out, int out_size, void* d_ws, size_t ws_size,
                              hipStream_t stream) {
    const float* hs    = (const float*)d_in[0];
    const float* qkv_w = (const float*)d_in[1];
    const float* g_w   = (const float*)d_in[2];
    const float* o_w   = (const float*)d_in[3];
    const float* q_nw  = (const float*)d_in[4];
    const float* k_nw  = (const float*)d_in[5];
    const int*   pos   = (const int*)d_in[6];

    _Float16* hs16   = (_Float16*)d_ws;                      // 3072*2048 (reused for attn out)
    _Float16* qkvw16 = hs16 + (size_t)T_LEN * HID_DIM;       // 4096*2048
    _Float16* ow16   = qkvw16 + (size_t)QKV_COLS * HID_DIM;  // 2048*2048
    _Float16* qkv16  = ow16 + (size_t)HID_DIM * HID_DIM;     // 3072*4096 (v region unused)
    _Float16* vtb    = qkv16 + (size_t)T_LEN * QKV_COLS;     // 1024*3072 (V transposed)
    float* gate = (float*)(vtb + (size_t)NKV * HD * T_LEN);
    float2* rope_tab = (float2*)(gate + (size_t)T_LEN * NKV);  // 3072*64*8B

    constexpr int NQW = (QKV_COLS * HID_DIM) / 2048;   // 4096
    // 1. prep: hs cast + gate + rope table + qkv_w cast
    prep_kernel<<<T_LEN + NQW, 256, 0, stream>>>(hs, g_w, pos, qkv_w,
                                                 hs16, gate, rope_tab, qkvw16);
    // 2. qkv projection: 192x256 tiles, 256 blocks; RMSNorm+RoPE fused
    gemm_mph<T_LEN, QKV_COLS, HID_DIM, 192, 256, 2, 4, 2, _Float16, true, true>
        <<<(T_LEN / 192) * (QKV_COLS / 256), 512, 0, stream>>>(
            hs16, qkvw16, qkv16, vtb, q_nw, k_nw, rope_tab);
    // 3. retention (384 blocks) + o_w cast riders (2048 blocks), flattened
    attn_mfma2<<<ATTN_BLKS + OW_RIDERS, 256, 0, stream>>>(qkv16, vtb, gate, hs16,
                                                          o_w, ow16);
    // 4. output projection: 192x128 tiles, 256 blocks (2 blocks/CU)
    gemm_mph<T_LEN, HID_DIM, HID_DIM, 192, 128, 4, 2, 4, float, false, false>
        <<<(T_LEN / 192) * (HID_DIM / 128), 512, 0, stream>>>(
            hs16, ow16, (float*)d_out, nullptr, nullptr, nullptr, nullptr);
    (void)in_sizes; (void)n_in; (void)out_size; (void)ws_size;
}